// Round 6
// baseline (690.496 us; speedup 1.0000x reference)
//
#include <hip/hip_runtime.h>
#include <math.h>

// Problem constants
#define B_   4
#define N_   2048
#define D_   1024
#define H_   16
#define d_   64
#define F_   2048
#define PAD_ 8192
#define FB_  4097
#define NC_  32
#define EPS_ 1e-6f
#define PI_F 3.14159265358979323846f
#define PI_D 3.14159265358979323846

typedef unsigned short ushort_t;
typedef short bf16x8 __attribute__((ext_vector_type(8)));
typedef float f32x4  __attribute__((ext_vector_type(4)));

#define GLD16(gp, lp) __builtin_amdgcn_global_load_lds( \
    (const __attribute__((address_space(1))) unsigned int*)(const void*)(gp), \
    (__attribute__((address_space(3))) unsigned int*)(void*)(lp), 16, 0, 0)

// round-to-nearest-even fp32 -> bf16 (bits), plus residual split
__device__ __forceinline__ ushort_t bf16_rne(float v) {
    unsigned b = __float_as_uint(v);
    unsigned rb = b + 0x7fffu + ((b >> 16) & 1u);
    return (ushort_t)(rb >> 16);
}
__device__ __forceinline__ void split_bf16(float v, ushort_t& h, ushort_t& l) {
    h = bf16_rne(v);
    float fh = __uint_as_float((unsigned)h << 16);
    l = bf16_rne(v - fh);
}

__device__ __forceinline__ float2 cmul(float2 a, float2 w) {
    return make_float2(a.x * w.x - a.y * w.y, a.x * w.y + a.y * w.x);
}
__device__ __forceinline__ float2 cmulc(float2 a, float2 w) {   // a * conj(w)
    return make_float2(a.x * w.x + a.y * w.y, a.y * w.x - a.x * w.y);
}

// ---------------------------------------------------------------------------
// Merged twiddle builder: radix-2 table (13*4096), radix-4 table (6*3072),
// R6: + featmap weight transposes Wt[mat][c][j] = W[mat_layer][j][c]
// (mats: 0=qfm L1, 1=qfm L2, 2=kfm L1, 3=kfm L2 — shared across all heads).
// ---------------------------------------------------------------------------
__global__ __launch_bounds__(256) void kern_twid(float2* __restrict__ twid,
                                                 float2* __restrict__ tw4,
                                                 const float* __restrict__ qfm_w,
                                                 const float* __restrict__ kfm_w,
                                                 float* __restrict__ Wt) {
    int idx = blockIdx.x * 256 + threadIdx.x;
    if (idx < 13 * 4096) {
        const int lh = idx >> 12, t = idx & 4095;
        const int hh = 1 << lh;
        const int j = t & (hh - 1);
        double s, c;
        sincos(-PI_D * (double)j / (double)hh, &s, &c);
        twid[idx] = make_float2((float)c, (float)s);
    } else {
        idx -= 13 * 4096;
        if (idx < 6 * 3072) {
            const int s = idx / 3072;
            const int r = idx - s * 3072;
            const int j = r / 3;
            const int m = r - 3 * j + 1;
            const int q = 1024 >> (2 * s);
            double sn, cs;
            sincos(-2.0 * PI_D * (double)(m * (j & (q - 1))) / (double)(4 * q), &sn, &cs);
            tw4[idx] = make_float2((float)cs, (float)sn);
        } else {
            idx -= 6 * 3072;
            if (idx < 4 * 4096) {
                const int mat = idx >> 12, e = idx & 4095;
                const int c = e >> 6, j = e & 63;
                const float* src = (mat < 2) ? qfm_w : kfm_w;
                const int l = mat & 1;
                Wt[mat * 4096 + c * 64 + j] = src[l * 4096 + j * 64 + c];
            }
        }
    }
}

// ---------------------------------------------------------------------------
// Merged split: three fp32 arrays -> (hi, lo) bf16 arrays in one launch
// ---------------------------------------------------------------------------
__global__ __launch_bounds__(256) void kern_split3(
        const float* __restrict__ s0, ushort_t* __restrict__ h0, ushort_t* __restrict__ l0, int n0,
        const float* __restrict__ s1, ushort_t* __restrict__ h1, ushort_t* __restrict__ l1, int n1,
        const float* __restrict__ s2, ushort_t* __restrict__ h2, ushort_t* __restrict__ l2, int n2) {
    int i = blockIdx.x * 256 + threadIdx.x;
    const float* s; ushort_t* hh; ushort_t* ll; int k;
    if (i < n0)                { s = s0; hh = h0; ll = l0; k = i; }
    else if (i < n0 + n1)      { s = s1; hh = h1; ll = l1; k = i - n0; }
    else if (i < n0 + n1 + n2) { s = s2; hh = h2; ll = l2; k = i - n0 - n1; }
    else return;
    ushort_t h, l;
    split_bf16(s[k], h, l);
    hh[k] = h; ll[k] = l;
}

// ---------------------------------------------------------------------------
// Split-bf16 MFMA NT GEMM: C = A*B^T + bias. 3 cross-products.
// 128x128 tile, BK=32, 256 thr. M, Nn, K multiples of 128.
// Stage-drain bound at the m97-structure ceiling (~954 TF raw).
// ---------------------------------------------------------------------------
__global__ __launch_bounds__(256) void gemm_mfma(
        const ushort_t* __restrict__ Ah, const ushort_t* __restrict__ Al, int lda,
        const ushort_t* __restrict__ Bh, const ushort_t* __restrict__ Bl, int ldb,
        const float* __restrict__ bias, float* __restrict__ C,
        int Nn, int K) {
    __shared__ __align__(16) ushort_t At0[128 * 32];
    __shared__ __align__(16) ushort_t At1[128 * 32];
    __shared__ __align__(16) ushort_t Bt0[128 * 32];
    __shared__ __align__(16) ushort_t Bt1[128 * 32];

    const int tid = threadIdx.x;
    const int wv = tid >> 6, lane = tid & 63;
    const int quad = lane >> 4, lrow = lane & 15;
    const int m0 = blockIdx.y * 128, n0 = blockIdx.x * 128;
    const int mw = (wv >> 1) * 64, nw = (wv & 1) * 64;

    const int srow = lane >> 2;
    const int schunk = (((lane & 3) ^ ((lane >> 3) & 3)) * 8);
    const int qsw = ((quad ^ ((lrow >> 1) & 3)) * 8);

    f32x4 acc[4][4] = {};

    for (int k0 = 0; k0 < K; k0 += 32) {
        {
            const size_t ga = (size_t)(m0 + wv * 32 + srow) * lda + k0 + schunk;
            const size_t gb = (size_t)(n0 + wv * 32 + srow) * ldb + k0 + schunk;
            const size_t ga2 = ga + (size_t)16 * lda;
            const size_t gb2 = gb + (size_t)16 * ldb;
            GLD16(Ah + ga,  &At0[(wv * 32) * 32]);
            GLD16(Ah + ga2, &At0[(wv * 32 + 16) * 32]);
            GLD16(Al + ga,  &At1[(wv * 32) * 32]);
            GLD16(Al + ga2, &At1[(wv * 32 + 16) * 32]);
            GLD16(Bh + gb,  &Bt0[(wv * 32) * 32]);
            GLD16(Bh + gb2, &Bt0[(wv * 32 + 16) * 32]);
            GLD16(Bl + gb,  &Bt1[(wv * 32) * 32]);
            GLD16(Bl + gb2, &Bt1[(wv * 32 + 16) * 32]);
        }
        __syncthreads();

        bf16x8 a0[4], a1[4], b0[4], b1[4];
#pragma unroll
        for (int i = 0; i < 4; ++i) {
            a0[i] = *(const bf16x8*)&At0[(mw + i * 16 + lrow) * 32 + qsw];
            a1[i] = *(const bf16x8*)&At1[(mw + i * 16 + lrow) * 32 + qsw];
            b0[i] = *(const bf16x8*)&Bt0[(nw + i * 16 + lrow) * 32 + qsw];
            b1[i] = *(const bf16x8*)&Bt1[(nw + i * 16 + lrow) * 32 + qsw];
        }
#pragma unroll
        for (int mi = 0; mi < 4; ++mi)
#pragma unroll
            for (int nj = 0; nj < 4; ++nj) {
                acc[mi][nj] = __builtin_amdgcn_mfma_f32_16x16x32_bf16(a0[mi], b0[nj], acc[mi][nj], 0, 0, 0);
                acc[mi][nj] = __builtin_amdgcn_mfma_f32_16x16x32_bf16(a0[mi], b1[nj], acc[mi][nj], 0, 0, 0);
                acc[mi][nj] = __builtin_amdgcn_mfma_f32_16x16x32_bf16(a1[mi], b0[nj], acc[mi][nj], 0, 0, 0);
            }
        __syncthreads();
    }

#pragma unroll
    for (int mi = 0; mi < 4; ++mi) {
        const int row = m0 + mw + mi * 16 + quad * 4;
#pragma unroll
        for (int nj = 0; nj < 4; ++nj) {
            const int col = n0 + nw + nj * 16 + lrow;
            const float bv = bias[col];
#pragma unroll
            for (int r = 0; r < 4; ++r)
                C[(size_t)(row + r) * Nn + col] = acc[mi][nj][r] + bv;
        }
    }
}

// ---------------------------------------------------------------------------
// M=4 GEMV for the control path
// ---------------------------------------------------------------------------
__device__ __forceinline__ float gelu_f(float x) {
    return 0.5f * x * (1.f + tanhf(0.7978845608028654f * (x + 0.044715f * x * x * x)));
}

__global__ __launch_bounds__(256) void kern_gemv4(const float* __restrict__ A,
                                                  const float* __restrict__ W,
                                                  const float* __restrict__ bias,
                                                  float* __restrict__ C,
                                                  int Nn, int act) {
    const int tid = threadIdx.x;
    const int wv = tid >> 6, lane = tid & 63;
    const int col = blockIdx.x * 4 + wv;
    const float* wp = W + (size_t)col * D_;
    float a0 = 0.f, a1 = 0.f, a2 = 0.f, a3 = 0.f;
#pragma unroll
    for (int i = 0; i < 16; ++i) {
        int k = lane + i * 64;
        float w = wp[k];
        a0 += A[k] * w;
        a1 += A[D_ + k] * w;
        a2 += A[2 * D_ + k] * w;
        a3 += A[3 * D_ + k] * w;
    }
    for (int m = 1; m < 64; m <<= 1) {
        a0 += __shfl_xor(a0, m);
        a1 += __shfl_xor(a1, m);
        a2 += __shfl_xor(a2, m);
        a3 += __shfl_xor(a3, m);
    }
    if (lane == 0) {
        float bv = bias[col];
        float v0 = a0 + bv, v1 = a1 + bv, v2 = a2 + bv, v3 = a3 + bv;
        if (act) { v0 = gelu_f(v0); v1 = gelu_f(v1); v2 = gelu_f(v2); v3 = gelu_f(v3); }
        C[0 * Nn + col] = v0;
        C[1 * Nn + col] = v1;
        C[2 * Nn + col] = v2;
        C[3 * Nn + col] = v3;
    }
}

// ---------------------------------------------------------------------------
// Featuremap + field build.
// R6: weights read from global pre-transposed Wt (L1-resident, shared by all
// 2048 blocks) instead of per-block LDS transposes. LDS 53->35 KB (4 blk/CU),
// 7 barriers (was 11), conflicted wbuf store eliminated. FMA sequence
// unchanged -> bit-identical results.
// ---------------------------------------------------------------------------
__global__ __launch_bounds__(256) void kern_feat(float* __restrict__ qkvg,
                                                 const float* __restrict__ Wt,
                                                 const float* __restrict__ qfm_b,
                                                 const float* __restrict__ kfm_b,
                                                 const float* __restrict__ wg_w,
                                                 const float* __restrict__ wg_b,
                                                 float* __restrict__ field) {
    __shared__ __align__(16) float in_t[64][68];
    __shared__ __align__(16) float tmp[64][68];
    __shared__ float wgbuf[64];

    const int tid = threadIdx.x;
    const int lane = tid & 63, grp = tid >> 6;
    const int n0 = blockIdx.x * 64;
    const int h = blockIdx.y, b = blockIdx.z;
    const size_t rowbase = (size_t)(b * N_ + n0) * 4096;

    const int lr4 = tid >> 4;          // 0..15 row within 16-row group
    const int lc4 = (tid & 15) * 4;    // 0,4,...,60 col

    // register-blocked MLP lane roles
    const int rg = lane >> 4;               // 0..3 row-group within wave's 16 rows
    const int cg4 = (lane & 15) * 4;        // 0,4,...,60 output col base
    const int rbase = grp * 16 + rg * 4;    // first of this lane's 4 rows

#define LOAD64x64(dst, off) \
    for (int it = 0; it < 4; ++it) { \
        int r = lr4 + it * 16; \
        float4 v = *(const float4*)&qkvg[rowbase + (size_t)r * 4096 + (off) + lc4]; \
        *(float4*)&dst[r][lc4] = v; \
    }

// acc[rr] (f32x4 over jj): acc[rr][jj] += in[rbase+rr][c]*Wg[c*64+cg4+jj]
#define MLP2_ACC(srcarr, Wg) \
    f32x4 acc[4] = {}; \
    for (int c4 = 0; c4 < 64; c4 += 4) { \
        f32x4 wv0 = *(const f32x4*)&(Wg)[(c4 + 0) * 64 + cg4]; \
        f32x4 wv1 = *(const f32x4*)&(Wg)[(c4 + 1) * 64 + cg4]; \
        f32x4 wv2 = *(const f32x4*)&(Wg)[(c4 + 2) * 64 + cg4]; \
        f32x4 wv3 = *(const f32x4*)&(Wg)[(c4 + 3) * 64 + cg4]; \
        _Pragma("unroll") for (int rr = 0; rr < 4; ++rr) { \
            f32x4 iv = *(const f32x4*)&srcarr[rbase + rr][c4]; \
            acc[rr] += wv0 * iv[0]; \
            acc[rr] += wv1 * iv[1]; \
            acc[rr] += wv2 * iv[2]; \
            acc[rr] += wv3 * iv[3]; \
        } \
    }

#define MLP2_STORE_LDS(dstarr, biasp, EPSV) { \
    f32x4 b4 = *(const f32x4*)&(biasp)[cg4]; \
    _Pragma("unroll") for (int rr = 0; rr < 4; ++rr) { \
        f32x4 v = acc[rr] + b4; \
        _Pragma("unroll") for (int k = 0; k < 4; ++k) v[k] = fmaxf(v[k], 0.f) + (EPSV); \
        *(f32x4*)&dstarr[rbase + rr][cg4] = v; } }

    // ============ K path ============
    LOAD64x64(in_t, D_ + h * 64)
    __syncthreads();
    if (tid < 64) {   // wg from raw k (wg_w read from global, uniform)
        float s = 0.f;
        for (int c4 = 0; c4 < 64; c4 += 4) {
            float4 iv = *(const float4*)&in_t[tid][c4];
            s += iv.x * wg_w[c4] + iv.y * wg_w[c4 + 1] + iv.z * wg_w[c4 + 2] + iv.w * wg_w[c4 + 3];
        }
        s += wg_b[0];
        wgbuf[tid] = 1.f / (1.f + expf(-s));
    }
    {   // K L1: tmp = relu(in_t @ W0^T + b0)
        MLP2_ACC(in_t, Wt + 2 * 4096)
        MLP2_STORE_LDS(tmp, kfm_b, 0.f)
    }
    __syncthreads();
    {   // K L2: phi_k -> in_t (+EPS)
        MLP2_ACC(tmp, Wt + 3 * 4096)
        MLP2_STORE_LDS(in_t, kfm_b + 64, EPS_)
    }
    __syncthreads();
    LOAD64x64(tmp, 2 * D_ + h * 64)     // V -> tmp
    __syncthreads();

    // field write: write[c<64] = wg*pk*v ; write[c>=64] = wg*pk
    {
        float* frow = field + (size_t)(b * H_ + h) * 128 * F_;
        const bool last = (n0 == N_ - 64);
        for (int c = grp; c < 128; c += 4) {
            int i = lane;
            float v = (c < 64) ? wgbuf[i] * in_t[i][c] * tmp[i][c]
                               : wgbuf[i] * in_t[i][c - 64];
            if (last) {
                if (i == 62) {
                    float v2 = (c < 64) ? wgbuf[63] * in_t[63][c] * tmp[63][c]
                                        : wgbuf[63] * in_t[63][c - 64];
                    v += v2;
                } else if (i == 63) v = 0.f;
            }
            frow[(size_t)c * F_ + n0 + i] = v;
        }
    }
    __syncthreads();

    // ============ Q path ============
    LOAD64x64(in_t, h * 64)
    __syncthreads();
    {   // Q L1
        MLP2_ACC(in_t, Wt)
        MLP2_STORE_LDS(tmp, qfm_b, 0.f)
    }
    __syncthreads();
    {   // Q L2: phi_q -> qkvg k-columns (global, f32x4 coalesced)
        MLP2_ACC(tmp, Wt + 4096)
        f32x4 b4 = *(const f32x4*)&qfm_b[64 + cg4];
#pragma unroll
        for (int rr = 0; rr < 4; ++rr) {
            f32x4 v = acc[rr] + b4;
#pragma unroll
            for (int k = 0; k < 4; ++k) v[k] = fmaxf(v[k], 0.f) + EPS_;
            *(f32x4*)&qkvg[rowbase + (size_t)(rbase + rr) * 4096 + D_ + h * 64 + cg4] = v;
        }
    }
#undef LOAD64x64
#undef MLP2_ACC
#undef MLP2_STORE_LDS
}

// ---------------------------------------------------------------------------
// LayerNorm of q token 0 -> q0n (B x 1024).
// ---------------------------------------------------------------------------
__global__ void kern_ln(const float* __restrict__ qkvg,
                        const float* __restrict__ ln_g,
                        const float* __restrict__ ln_b,
                        float* __restrict__ q0n) {
    const int bh = blockIdx.x, c = threadIdx.x;
    const int b = bh >> 4, h = bh & 15;
    float x = qkvg[(size_t)(b * N_) * 4096 + h * 64 + c];
    float mu = x;
    for (int m = 1; m < 64; m <<= 1) mu += __shfl_xor(mu, m);
    mu *= (1.f / 64.f);
    float dv = (x - mu) * (x - mu);
    for (int m = 1; m < 64; m <<= 1) dv += __shfl_xor(dv, m);
    float var = dv * (1.f / 64.f);
    q0n[b * 1024 + h * 64 + c] = (x - mu) * rsqrtf(var + 1e-5f) * ln_g[c] + ln_b[c];
}

// ---------------------------------------------------------------------------
// Templated table-driven radix-2 FFT helpers (used by kern_prep).
// ---------------------------------------------------------------------------
template <int NT>
__device__ __forceinline__ void fft_fwd_dif_t(float* xr, float* xi, int tid, int logn,
                                              const float2* __restrict__ twid) {
    const int nb = 1 << (logn - 1);
    for (int lh = logn - 1; lh >= 0; --lh) {
        const int hh = 1 << lh;
        const float2* tws = twid + lh * 4096;
        for (int t = tid; t < nb; t += NT) {
            int j = t & (hh - 1);
            int i1 = ((t >> lh) << (lh + 1)) | j;
            int i2 = i1 + hh;
            float2 tw = tws[t];
            float ar = xr[i1], ai = xi[i1];
            float br = xr[i2], bi = xi[i2];
            xr[i1] = ar + br; xi[i1] = ai + bi;
            float tr = ar - br, ti = ai - bi;
            xr[i2] = tr * tw.x - ti * tw.y;
            xi[i2] = tr * tw.y + ti * tw.x;
        }
        __syncthreads();
    }
}

template <int NT>
__device__ __forceinline__ void fft_inv_dit_t(float* xr, float* xi, int tid, int logn,
                                              const float2* __restrict__ twid) {
    const int nb = 1 << (logn - 1);
    for (int lh = 0; lh < logn; ++lh) {
        const int hh = 1 << lh;
        const float2* tws = twid + lh * 4096;
        for (int t = tid; t < nb; t += NT) {
            int j = t & (hh - 1);
            int i1 = ((t >> lh) << (lh + 1)) | j;
            int i2 = i1 + hh;
            float2 tw = tws[t];   // conj applied
            float br = xr[i2], bi = xi[i2];
            float tr = br * tw.x + bi * tw.y;
            float ti = bi * tw.x - br * tw.y;
            float ar = xr[i1], ai = xi[i1];
            xr[i1] = ar + tr; xi[i1] = ai + ti;
            xr[i2] = ar - tr; xi[i2] = ai - ti;
        }
        __syncthreads();
    }
}

// Padded LDS indexing for kern_prep's radix-4 helper (R2).
#define ZIDX(i) ((i) + ((i) >> 4))

// Generic radix-4 fwd stage range [SBEG, SEND) — used by kern_prep only.
template <int NT, int SBEG, int SEND>
__device__ __forceinline__ void fft4_fwd_stages(float2* z, int tid,
                                                const float2* __restrict__ tw4) {
#pragma unroll
    for (int s = SBEG; s < SEND; ++s) {
        const int q = 1024 >> (2 * s);
        const int qq = q + (q >> 4);
        const float2* tws = tw4 + s * 3072;
        for (int t = tid; t < 1024; t += NT) {
            int j = t & (q - 1);
            int base = ((t & ~(q - 1)) << 2) | j;
            int i0, i1, i2, i3;
            if (q >= 16) { i0 = ZIDX(base); i1 = i0 + qq; i2 = i1 + qq; i3 = i2 + qq; }
            else { i0 = ZIDX(base); i1 = ZIDX(base + q); i2 = ZIDX(base + 2 * q); i3 = ZIDX(base + 3 * q); }
            float2 a = z[i0], b = z[i1], c = z[i2], d = z[i3];
            float2 s0 = make_float2(a.x + c.x, a.y + c.y);
            float2 s1 = make_float2(a.x - c.x, a.y - c.y);
            float2 s2 = make_float2(b.x + d.x, b.y + d.y);
            float2 s3 = make_float2(b.x - d.x, b.y - d.y);
            float2 m1 = make_float2(s1.x + s3.y, s1.y - s3.x);
            float2 m2 = make_float2(s0.x - s2.x, s0.y - s2.y);
            float2 m3 = make_float2(s1.x - s3.y, s1.y + s3.x);
            z[i0] = make_float2(s0.x + s2.x, s0.y + s2.y);
            z[i1] = cmul(m1, tws[3 * j + 0]);
            z[i2] = cmul(m2, tws[3 * j + 1]);
            z[i3] = cmul(m3, tws[3 * j + 2]);
        }
        __syncthreads();
    }
}

// ---------------------------------------------------------------------------
// Register radix-4 butterflies for the fused conv4 (R5). Bit-exact math.
// ---------------------------------------------------------------------------
__device__ __forceinline__ void bf4_fwd(float2& e0, float2& e1, float2& e2, float2& e3,
                                        const float2* __restrict__ tws, int j) {
    float2 a = e0, b = e1, c = e2, d = e3;
    float2 s0 = make_float2(a.x + c.x, a.y + c.y);
    float2 s1 = make_float2(a.x - c.x, a.y - c.y);
    float2 s2 = make_float2(b.x + d.x, b.y + d.y);
    float2 s3 = make_float2(b.x - d.x, b.y - d.y);
    float2 m1 = make_float2(s1.x + s3.y, s1.y - s3.x);
    float2 m2 = make_float2(s0.x - s2.x, s0.y - s2.y);
    float2 m3 = make_float2(s1.x - s3.y, s1.y + s3.x);
    e0 = make_float2(s0.x + s2.x, s0.y + s2.y);
    e1 = cmul(m1, tws[3 * j + 0]);
    e2 = cmul(m2, tws[3 * j + 1]);
    e3 = cmul(m3, tws[3 * j + 2]);
}
__device__ __forceinline__ void bf4_fwd_id(float2& e0, float2& e1, float2& e2, float2& e3) {
    float2 a = e0, b = e1, c = e2, d = e3;
    float2 s0 = make_float2(a.x + c.x, a.y + c.y);
    float2 s1 = make_float2(a.x - c.x, a.y - c.y);
    float2 s2 = make_float2(b.x + d.x, b.y + d.y);
    float2 s3 = make_float2(b.x - d.x, b.y - d.y);
    e0 = make_float2(s0.x + s2.x, s0.y + s2.y);
    e1 = make_float2(s1.x + s3.y, s1.y - s3.x);
    e2 = make_float2(s0.x - s2.x, s0.y - s2.y);
    e3 = make_float2(s1.x - s3.y, s1.y + s3.x);
}
__device__ __forceinline__ void bf4_inv(float2& e0, float2& e1, float2& e2, float2& e3,
                                        const float2* __restrict__ tws, int j) {
    float2 a = e0;
    float2 b = cmulc(e1, tws[3 * j + 0]);
    float2 c = cmulc(e2, tws[3 * j + 1]);
    float2 d = cmulc(e3, tws[3 * j + 2]);
    float2 p0 = make_float2(a.x + c.x, a.y + c.y);
    float2 p1 = make_float2(a.x - c.x, a.y - c.y);
    float2 p2 = make_float2(b.x + d.x, b.y + d.y);
    float2 p3 = make_float2(b.x - d.x, b.y - d.y);
    e0 = make_float2(p0.x + p2.x, p0.y + p2.y);
    e1 = make_float2(p1.x - p3.y, p1.y + p3.x);
    e2 = make_float2(p0.x - p2.x, p0.y - p2.y);
    e3 = make_float2(p1.x + p3.y, p1.y - p3.x);
}
__device__ __forceinline__ void bf4_inv_id(float2& e0, float2& e1, float2& e2, float2& e3) {
    float2 a = e0, b = e1, c = e2, d = e3;
    float2 p0 = make_float2(a.x + c.x, a.y + c.y);
    float2 p1 = make_float2(a.x - c.x, a.y - c.y);
    float2 p2 = make_float2(b.x + d.x, b.y + d.y);
    float2 p3 = make_float2(b.x - d.x, b.y - d.y);
    e0 = make_float2(p0.x + p2.x, p0.y + p2.y);
    e1 = make_float2(p1.x - p3.y, p1.y + p3.x);
    e2 = make_float2(p0.x - p2.x, p0.y - p2.y);
    e3 = make_float2(p1.x + p3.y, p1.y - p3.x);
}

// ---------------------------------------------------------------------------
// Merged prep (1024 threads, per (b,h)): build damped-cosine kernel, fwd 8192
// FFT, apply gate in BR order, inv FFT, fold to 4096, radix-4 fwd -> GBR.
// Final radix-4 stage fused into the GBR store, 1/4096 scale folded in.
// ---------------------------------------------------------------------------
__global__ __launch_bounds__(1024) void kern_prep(const float* __restrict__ freq,
                                                  const float* __restrict__ damp,
                                                  const float* __restrict__ phase,
                                                  const float* __restrict__ ctrl,
                                                  const float2* __restrict__ twid,
                                                  const float2* __restrict__ tw4,
                                                  float* __restrict__ GBR) {
    __shared__ float sm[2 * PAD_];    // 64 KB
    float* xr = sm;
    float* xi = sm + PAD_;
    const int bh = blockIdx.x, tid = threadIdx.x;
    const int b = bh >> 4, h = bh & 15;

    // build kernel in time domain
    const float fr = freq[h], ed = expf(damp[h]), ph = phase[h];
    for (int f = tid; f < PAD_; f += 1024) {
        float v = 0.f;
        if (f < F_) {
            float t = (float)f / (float)F_;
            v = expf(-ed * t) * cosf(fr * t + ph);
        }
        xr[f] = v; xi[f] = 0.f;
    }
    __syncthreads();
    fft_fwd_dif_t<1024>(xr, xi, tid, 13, twid);   // natural -> BR spectrum

    // gate in BR order
    const float* cp = ctrl + b * (H_ * NC_) + h * NC_;
    for (int j = tid; j < PAD_; j += 1024) {
        int k = (int)(__brev((unsigned)j) >> 19);
        int kk = min(k, PAD_ - k);
        float ip = (float)kk * ((float)(NC_ - 1) / (float)(FB_ - 1));
        int il = min((int)ip, NC_ - 2);
        float iw = ip - (float)il;
        float m = 1.f + cp[il] * (1.f - iw) + cp[il + 1] * iw;
        xr[j] *= m;
        xi[j] *= m;
    }
    __syncthreads();
    fft_inv_dit_t<1024>(xr, xi, tid, 13, twid);   // BR -> natural keff (unscaled)

    // fold to 4096 real kernel, staged through registers
    float g[4];
    const float sc = 1.f / (float)PAD_;
#pragma unroll
    for (int u = 0; u < 4; ++u) {
        int j = tid + u * 1024;
        g[u] = ((j < 2048) ? xr[j] : xr[j + 4096]) * sc;
    }
    __syncthreads();
    float2* z = (float2*)sm;
#pragma unroll
    for (int u = 0; u < 4; ++u) {
        int j = tid + u * 1024;
        z[ZIDX(j)] = make_float2(g[u], 0.f);
    }
    __syncthreads();
    fft4_fwd_stages<1024, 0, 5>(z, tid, tw4);     // stages 0..4
    // fused final stage (q=1, identity twiddles) -> GBR global, scaled 1/4096
    {
        const float sc2 = 1.f / 4096.f;
        const int t = tid;   // 1024 threads, one butterfly each
        const int base = t << 2;
        float2 a = z[ZIDX(base)], bq = z[ZIDX(base + 1)];
        float2 c = z[ZIDX(base + 2)], dq = z[ZIDX(base + 3)];
        float2 s0 = make_float2(a.x + c.x, a.y + c.y);
        float2 s1 = make_float2(a.x - c.x, a.y - c.y);
        float2 s2 = make_float2(bq.x + dq.x, bq.y + dq.y);
        float2 s3 = make_float2(bq.x - dq.x, bq.y - dq.y);
        float2 o0 = make_float2(s0.x + s2.x, s0.y + s2.y);
        float2 o1 = make_float2(s1.x + s3.y, s1.y - s3.x);
        float2 o2 = make_float2(s0.x - s2.x, s0.y - s2.y);
        float2 o3 = make_float2(s1.x - s3.y, s1.y + s3.x);
        float2* Gp = (float2*)GBR + (size_t)bh * 4096 + base;
        Gp[0] = make_float2(o0.x * sc2, o0.y * sc2);
        Gp[1] = make_float2(o1.x * sc2, o1.y * sc2);
        Gp[2] = make_float2(o2.x * sc2, o2.y * sc2);
        Gp[3] = make_float2(o3.x * sc2, o3.y * sc2);
    }
}

// ---------------------------------------------------------------------------
// Main conv (R5): register-fused double stages, 5 LDS passes, 4 barriers.
// ---------------------------------------------------------------------------
#define LIDX(i) ((i) ^ (((i) >> 4) & 15))

__global__ __launch_bounds__(256) void kern_conv4(float* __restrict__ field,
                                                  const float* __restrict__ GBR,
                                                  const float2* __restrict__ tw4) {
    __shared__ float2 z[4096];
    const int tid = threadIdx.x;
    const int bh = blockIdx.x >> 6, cp = blockIdx.x & 63;
    float* rowx = field + ((size_t)bh * 128 + 2 * cp) * F_;
    float* rowy = rowx + F_;
    const float2* tws0 = tw4;
    const float2* tws1 = tw4 + 3072;
    const float2* tws2 = tw4 + 2 * 3072;
    const float2* tws3 = tw4 + 3 * 3072;
    const float2* tws4s = tw4 + 4 * 3072;

    float2 x[16];

    // ---- P1: load + fwd stages 0 (q=1024), 1 (q=256) ----
    {
        const int j16 = tid;
#pragma unroll
        for (int m = 0; m < 8; ++m)
            x[m] = make_float2(rowx[j16 + 256 * m], rowy[j16 + 256 * m]);
#pragma unroll
        for (int m = 8; m < 16; ++m) x[m] = make_float2(0.f, 0.f);
#pragma unroll
        for (int r = 0; r < 4; ++r)
            bf4_fwd(x[r], x[r + 4], x[r + 8], x[r + 12], tws0, j16 + 256 * r);
#pragma unroll
        for (int c = 0; c < 4; ++c)
            bf4_fwd(x[4 * c], x[4 * c + 1], x[4 * c + 2], x[4 * c + 3], tws1, j16);
#pragma unroll
        for (int m = 0; m < 16; ++m) z[LIDX(j16 + 256 * m)] = x[m];
    }
    __syncthreads();

    // ---- P2: fwd stages 2 (q=64), 3 (q=16) ----
    {
        const int j16 = tid & 15;
        const int pb = (tid >> 4) * 256 + j16;
#pragma unroll
        for (int m = 0; m < 16; ++m) x[m] = z[LIDX(pb + 16 * m)];
#pragma unroll
        for (int r = 0; r < 4; ++r)
            bf4_fwd(x[r], x[r + 4], x[r + 8], x[r + 12], tws2, j16 + 16 * r);
#pragma unroll
        for (int c = 0; c < 4; ++c)
            bf4_fwd(x[4 * c], x[4 * c + 1], x[4 * c + 2], x[4 * c + 3], tws3, j16);
#pragma unroll
        for (int m = 0; m < 16; ++m) z[LIDX(pb + 16 * m)] = x[m];
    }
    __syncthreads();

    // ---- P3: fwd stages 4 (q=4), 5 (q=1,id) + G + inv 5 (id), 4 ----
    {
        const int pb = tid * 16;
#pragma unroll
        for (int m = 0; m < 16; ++m) x[m] = z[LIDX(pb + m)];
#pragma unroll
        for (int r = 0; r < 4; ++r)
            bf4_fwd(x[r], x[r + 4], x[r + 8], x[r + 12], tws4s, r);
#pragma unroll
        for (int c = 0; c < 4; ++c)
            bf4_fwd_id(x[4 * c], x[4 * c + 1], x[4 * c + 2], x[4 * c + 3]);
        const float2* G = (const float2*)GBR + (size_t)bh * 4096 + pb;
#pragma unroll
        for (int m = 0; m < 16; ++m) x[m] = cmul(x[m], G[m]);
#pragma unroll
        for (int c = 0; c < 4; ++c)
            bf4_inv_id(x[4 * c], x[4 * c + 1], x[4 * c + 2], x[4 * c + 3]);
#pragma unroll
        for (int r = 0; r < 4; ++r)
            bf4_inv(x[r], x[r + 4], x[r + 8], x[r + 12], tws4s, r);
#pragma unroll
        for (int m = 0; m < 16; ++m) z[LIDX(pb + m)] = x[m];
    }
    __syncthreads();

    // ---- P4: inv stages 3 (q=16), 2 (q=64) ----
    {
        const int j16 = tid & 15;
        const int pb = (tid >> 4) * 256 + j16;
#pragma unroll
        for (int m = 0; m < 16; ++m) x[m] = z[LIDX(pb + 16 * m)];
#pragma unroll
        for (int c = 0; c < 4; ++c)
            bf4_inv(x[4 * c], x[4 * c + 1], x[4 * c + 2], x[4 * c + 3], tws3, j16);
#pragma unroll
        for (int r = 0; r < 4; ++r)
            bf4_inv(x[r], x[r + 4], x[r + 8], x[r + 12], tws2, j16 + 16 * r);
#pragma unroll
        for (int m = 0; m < 16; ++m) z[LIDX(pb + 16 * m)] = x[m];
    }
    __syncthreads();

    // ---- P5: inv stages 1 (q=256), 0 (q=1024) + store (p < 2048) ----
    {
        const int j16 = tid;
#pragma unroll
        for (int m = 0; m < 16; ++m) x[m] = z[LIDX(j16 + 256 * m)];
#pragma unroll
        for (int c = 0; c < 4; ++c)
            bf4_inv(x[4 * c], x[4 * c + 1], x[4 * c + 2], x[4 * c + 3], tws1, j16);
#pragma unroll
        for (int r = 0; r < 4; ++r)
            bf4_inv(x[r], x[r + 4], x[r + 8], x[r + 12], tws0, j16 + 256 * r);
#pragma unroll
        for (int m = 0; m < 8; ++m) {
            rowx[j16 + 256 * m] = x[m].x;
            rowy[j16 + 256 * m] = x[m].y;
        }
    }
}

// ---------------------------------------------------------------------------
// combine (LDS-staged g-plane gather from R2).
// ---------------------------------------------------------------------------
__global__ __launch_bounds__(1024) void kern_combine(float* __restrict__ qkvg,
                                                     const float* __restrict__ field,
                                                     const float* __restrict__ coupling) {
    __shared__ float cpl[16][16];
    __shared__ float sbuf[2][128][17];
    const int tid = threadIdx.x;
    if (tid < 256) cpl[tid >> 4][tid & 15] = coupling[tid];
    const int lane = tid & 63, wv = tid >> 6;
    const int n = blockIdx.x * 16 + wv;
    const int b = blockIdx.y;
    const int f0 = blockIdx.x * 16;
    const int fi = min(n, F_ - 2) - f0;   // 0..15 (last block: clamped to 14)
    const size_t row = (size_t)(b * N_ + n) * 4096;

    // loader role: c = tid>>3 (0..127), k = (tid&7)*2
    const int lc = tid >> 3, lk = (tid & 7) * 2;
    const float* fb = field + (size_t)b * 16 * 128 * F_;

    float2 rv = *(const float2*)&fb[(size_t)lc * F_ + f0 + lk];   // slice g=0
    __syncthreads();                       // cpl visible before any reads
    sbuf[0][lc][lk] = rv.x; sbuf[0][lc][lk + 1] = rv.y;

    float ynum[16], yden[16];
#pragma unroll
    for (int hh = 0; hh < 16; ++hh) { ynum[hh] = 0.f; yden[hh] = 0.f; }

    for (int g = 0; g < 16; ++g) {
        if (g < 15)
            rv = *(const float2*)&fb[((size_t)(g + 1) * 128 + lc) * F_ + f0 + lk];
        __syncthreads();                   // sbuf[g&1] writes done; prior reads of sbuf[(g+1)&1] done
        const float nv = sbuf[g & 1][lane][fi];
        const float dv = sbuf[g & 1][64 + lane][fi];
#pragma unroll
        for (int hh = 0; hh < 16; ++hh) {
            const float cg = cpl[hh][g];
            ynum[hh] += cg * nv;
            yden[hh] += cg * dv;
        }
        if (g < 15) { sbuf[(g + 1) & 1][lc][lk] = rv.x; sbuf[(g + 1) & 1][lc][lk + 1] = rv.y; }
    }

    ushort_t* rp = (ushort_t*)(qkvg + row);
#pragma unroll
    for (int hh = 0; hh < 16; ++hh) {
        float pq = qkvg[row + D_ + hh * 64 + lane];
        float gv = qkvg[row + 3 * D_ + hh * 64 + lane];
        float s = pq * yden[hh];
        for (int m = 1; m < 64; m <<= 1) s += __shfl_xor(s, m);
        float den = fabsf(s) + 1e-4f;
        float o = pq * ynum[hh] / den * (1.f / (1.f + expf(-gv)));
        ushort_t oh, ol;
        split_bf16(o, oh, ol);
        rp[hh * 64 + lane] = oh;
        rp[1024 + hh * 64 + lane] = ol;
    }
}

// ---------------------------------------------------------------------------
extern "C" void kernel_launch(void* const* d_in, const int* in_sizes, int n_in,
                              void* d_out, int out_size, void* d_ws, size_t ws_size,
                              hipStream_t stream) {
    const float* x      = (const float*)d_in[0];
    const float* w_qkvg = (const float*)d_in[1];
    const float* b_qkvg = (const float*)d_in[2];
    const float* w_out  = (const float*)d_in[3];
    const float* b_out  = (const float*)d_in[4];
    const float* qfm_w  = (const float*)d_in[5];
    const float* qfm_b  = (const float*)d_in[6];
    const float* kfm_w  = (const float*)d_in[7];
    const float* kfm_b  = (const float*)d_in[8];
    const float* wg_w   = (const float*)d_in[9];
    const float* wg_b   = (const float*)d_in[10];
    const float* ln_g   = (const float*)d_in[11];
    const float* ln_b   = (const float*)d_in[12];
    const float* sg_w1  = (const float*)d_in[13];
    const float* sg_b1  = (const float*)d_in[14];
    const float* sg_w2  = (const float*)d_in[15];
    const float* sg_b2  = (const float*)d_in[16];
    const float* wfreq  = (const float*)d_in[17];
    const float* wdamp  = (const float*)d_in[18];
    const float* wphase = (const float*)d_in[19];
    const float* coup   = (const float*)d_in[20];

    float* ws = (float*)d_ws;
    // workspace (floats):
    float*  qkvg   = ws;                 // 33,554,432
    float*  field  = ws + 33554432;      // 16,777,216
    float*  GBR    = ws + 50593792;      //    524,288
    float2* twid   = (float2*)(ws + 51118080);   // 106,496 floats (radix-2)
    float*  q0n    = ws + 51224576;      //      4,096
    float*  h1     = ws + 51228672;      //      4,096
    float*  ctrl   = ws + 51232768;      //      2,048
    ushort_t* wouth = (ushort_t*)(ws + 51234816); // 524,288 floats
    ushort_t* woutl = (ushort_t*)(ws + 51759104); // 524,288 floats
    float2* tw4    = (float2*)(ws + 52283392);    // 36,864 floats (radix-4)
    float*  Wt     = ws + 52320256;      //     16,384 (4 x 64x64 transposed featmap weights)
    // end: 52,336,640 floats = 209.3 MB

    // bf16 staging aliases inside `field` (consumed by gemm#1 before feat writes)
    ushort_t* xh  = (ushort_t*)(field);
    ushort_t* xl  = (ushort_t*)(field + 4194304);
    ushort_t* wqh = (ushort_t*)(field + 8388608);
    ushort_t* wql = (ushort_t*)(field + 10485760);

    // 0. twiddles + featmap weight transposes (merged) + splits (merged)
    kern_twid<<<(13 * 4096 + 6 * 3072 + 4 * 4096) / 256, 256, 0, stream>>>(
        twid, tw4, qfm_w, kfm_w, Wt);
    kern_split3<<<(B_ * N_ * D_ + 4 * D_ * D_ + D_ * D_) / 256, 256, 0, stream>>>(
        x, xh, xl, B_ * N_ * D_,
        w_qkvg, wqh, wql, 4 * D_ * D_,
        w_out, wouth, woutl, D_ * D_);

    // 1. qkvg = x @ w_qkvg^T + b_qkvg   (split-bf16 MFMA; 4 M-slices for
    //    profiler visibility — same total work)
    for (int l = 0; l < 4; ++l) {
        const size_t aoff = (size_t)l * 2048 * D_;
        gemm_mfma<<<dim3(4096 / 128, 2048 / 128), 256, 0, stream>>>(
            xh + aoff, xl + aoff, D_, wqh, wql, D_, b_qkvg,
            qkvg + (size_t)l * 2048 * 4096, 4 * D_, D_);
    }

    // 2. control path: LN + two M=4 GEMVs
    kern_ln<<<B_ * H_, 64, 0, stream>>>(qkvg, ln_g, ln_b, q0n);
    kern_gemv4<<<D_ / 4, 256, 0, stream>>>(q0n, sg_w1, sg_b1, h1, D_, 1);
    kern_gemv4<<<(H_ * NC_) / 4, 256, 0, stream>>>(h1, sg_w2, sg_b2, ctrl, H_ * NC_, 0);

    // 3. spectra prep (merged base FFT + gate + fold, 1024 thr)
    kern_prep<<<B_ * H_, 1024, 0, stream>>>(wfreq, wdamp, wphase, ctrl, twid, tw4, GBR);

    // 4. featmaps + wg + field build (global pre-transposed weights)
    kern_feat<<<dim3(N_ / 64, H_, B_), 256, 0, stream>>>(
        qkvg, Wt, qfm_b, kfm_b, wg_w, wg_b, field);

    // 5. FFT convolution (register-fused radix-16 passes, 256 thr)
    kern_conv4<<<B_ * H_ * 64, 256, 0, stream>>>(field, GBR, tw4);

    // 6. combine (+fused coupling, LDS-staged) -> qkvg q-columns
    kern_combine<<<dim3(N_ / 16, B_), 1024, 0, stream>>>(qkvg, field, coup);

    // 7. out = att @ w_out^T + b_out
    gemm_mfma<<<dim3(1024 / 128, 8192 / 128), 256, 0, stream>>>(
        (ushort_t*)qkvg, (ushort_t*)qkvg + 1024, 8192,
        wouth, woutl, D_, b_out, (float*)d_out, D_, D_);
}

// Round 8
// 687.075 us; speedup vs baseline: 1.0050x; 1.0050x over previous
//
#include <hip/hip_runtime.h>
#include <math.h>

// Problem constants
#define B_   4
#define N_   2048
#define D_   1024
#define H_   16
#define d_   64
#define F_   2048
#define PAD_ 8192
#define FB_  4097
#define NC_  32
#define EPS_ 1e-6f
#define PI_F 3.14159265358979323846f
#define PI_D 3.14159265358979323846

typedef unsigned short ushort_t;
typedef short bf16x8 __attribute__((ext_vector_type(8)));
typedef float f32x4  __attribute__((ext_vector_type(4)));

#define GLD16(gp, lp) __builtin_amdgcn_global_load_lds( \
    (const __attribute__((address_space(1))) unsigned int*)(const void*)(gp), \
    (__attribute__((address_space(3))) unsigned int*)(void*)(lp), 16, 0, 0)

// round-to-nearest-even fp32 -> bf16 (bits), plus residual splits
__device__ __forceinline__ ushort_t bf16_rne(float v) {
    unsigned b = __float_as_uint(v);
    unsigned rb = b + 0x7fffu + ((b >> 16) & 1u);
    return (ushort_t)(rb >> 16);
}
__device__ __forceinline__ void split_bf16(float v, ushort_t& h, ushort_t& l) {
    h = bf16_rne(v);
    float fh = __uint_as_float((unsigned)h << 16);
    l = bf16_rne(v - fh);
}
// 3-term split: v = h + m + l with ~2^-27 relative error (24 mantissa bits)
__device__ __forceinline__ void split3_bf16(float v, ushort_t& h, ushort_t& m, ushort_t& l) {
    h = bf16_rne(v);
    float fh = __uint_as_float((unsigned)h << 16);
    float r = v - fh;
    m = bf16_rne(r);
    float fm = __uint_as_float((unsigned)m << 16);
    l = bf16_rne(r - fm);
}

__device__ __forceinline__ float2 cmul(float2 a, float2 w) {
    return make_float2(a.x * w.x - a.y * w.y, a.x * w.y + a.y * w.x);
}
__device__ __forceinline__ float2 cmulc(float2 a, float2 w) {   // a * conj(w)
    return make_float2(a.x * w.x + a.y * w.y, a.y * w.x - a.x * w.y);
}

// ---------------------------------------------------------------------------
// Merged twiddle builder: radix-2 table (13*4096), radix-4 table (6*3072),
// R8: + featmap weight 3-term bf16 split (original [j][c] layout = the
// K-contiguous row layout MFMA B-frags want). mats: 0=qfm L1, 1=qfm L2,
// 2=kfm L1, 3=kfm L2 (shared across all heads).
// ---------------------------------------------------------------------------
__global__ __launch_bounds__(256) void kern_twid(float2* __restrict__ twid,
                                                 float2* __restrict__ tw4,
                                                 const float* __restrict__ qfm_w,
                                                 const float* __restrict__ kfm_w,
                                                 ushort_t* __restrict__ Wfh,
                                                 ushort_t* __restrict__ Wfm,
                                                 ushort_t* __restrict__ Wfl) {
    int idx = blockIdx.x * 256 + threadIdx.x;
    if (idx < 13 * 4096) {
        const int lh = idx >> 12, t = idx & 4095;
        const int hh = 1 << lh;
        const int j = t & (hh - 1);
        double s, c;
        sincos(-PI_D * (double)j / (double)hh, &s, &c);
        twid[idx] = make_float2((float)c, (float)s);
    } else {
        idx -= 13 * 4096;
        if (idx < 6 * 3072) {
            const int s = idx / 3072;
            const int r = idx - s * 3072;
            const int j = r / 3;
            const int m = r - 3 * j + 1;
            const int q = 1024 >> (2 * s);
            double sn, cs;
            sincos(-2.0 * PI_D * (double)(m * (j & (q - 1))) / (double)(4 * q), &sn, &cs);
            tw4[idx] = make_float2((float)cs, (float)sn);
        } else {
            idx -= 6 * 3072;
            if (idx < 4 * 4096) {
                const int mat = idx >> 12, e = idx & 4095;
                const float* src = (mat < 2) ? qfm_w : kfm_w;
                float v = src[(mat & 1) * 4096 + e];
                ushort_t hh, mm, ll;
                split3_bf16(v, hh, mm, ll);
                Wfh[mat * 4096 + e] = hh;
                Wfm[mat * 4096 + e] = mm;
                Wfl[mat * 4096 + e] = ll;
            }
        }
    }
}

// ---------------------------------------------------------------------------
// Merged split: three fp32 arrays -> (hi, lo) bf16 arrays in one launch
// ---------------------------------------------------------------------------
__global__ __launch_bounds__(256) void kern_split3(
        const float* __restrict__ s0, ushort_t* __restrict__ h0, ushort_t* __restrict__ l0, int n0,
        const float* __restrict__ s1, ushort_t* __restrict__ h1, ushort_t* __restrict__ l1, int n1,
        const float* __restrict__ s2, ushort_t* __restrict__ h2, ushort_t* __restrict__ l2, int n2) {
    int i = blockIdx.x * 256 + threadIdx.x;
    const float* s; ushort_t* hh; ushort_t* ll; int k;
    if (i < n0)                { s = s0; hh = h0; ll = l0; k = i; }
    else if (i < n0 + n1)      { s = s1; hh = h1; ll = l1; k = i - n0; }
    else if (i < n0 + n1 + n2) { s = s2; hh = h2; ll = l2; k = i - n0 - n1; }
    else return;
    ushort_t h, l;
    split_bf16(s[k], h, l);
    hh[k] = h; ll[k] = l;
}

// ---------------------------------------------------------------------------
// Split-bf16 MFMA NT GEMM: C = A*B^T + bias. 3 cross-products.
// 128x128 tile, BK=32, 256 thr. M, Nn, K multiples of 128.
// Stage-drain bound at the m97-structure ceiling (~954 TF raw).
// ---------------------------------------------------------------------------
__global__ __launch_bounds__(256) void gemm_mfma(
        const ushort_t* __restrict__ Ah, const ushort_t* __restrict__ Al, int lda,
        const ushort_t* __restrict__ Bh, const ushort_t* __restrict__ Bl, int ldb,
        const float* __restrict__ bias, float* __restrict__ C,
        int Nn, int K) {
    __shared__ __align__(16) ushort_t At0[128 * 32];
    __shared__ __align__(16) ushort_t At1[128 * 32];
    __shared__ __align__(16) ushort_t Bt0[128 * 32];
    __shared__ __align__(16) ushort_t Bt1[128 * 32];

    const int tid = threadIdx.x;
    const int wv = tid >> 6, lane = tid & 63;
    const int quad = lane >> 4, lrow = lane & 15;
    const int m0 = blockIdx.y * 128, n0 = blockIdx.x * 128;
    const int mw = (wv >> 1) * 64, nw = (wv & 1) * 64;

    const int srow = lane >> 2;
    const int schunk = (((lane & 3) ^ ((lane >> 3) & 3)) * 8);
    const int qsw = ((quad ^ ((lrow >> 1) & 3)) * 8);

    f32x4 acc[4][4] = {};

    for (int k0 = 0; k0 < K; k0 += 32) {
        {
            const size_t ga = (size_t)(m0 + wv * 32 + srow) * lda + k0 + schunk;
            const size_t gb = (size_t)(n0 + wv * 32 + srow) * ldb + k0 + schunk;
            const size_t ga2 = ga + (size_t)16 * lda;
            const size_t gb2 = gb + (size_t)16 * ldb;
            GLD16(Ah + ga,  &At0[(wv * 32) * 32]);
            GLD16(Ah + ga2, &At0[(wv * 32 + 16) * 32]);
            GLD16(Al + ga,  &At1[(wv * 32) * 32]);
            GLD16(Al + ga2, &At1[(wv * 32 + 16) * 32]);
            GLD16(Bh + gb,  &Bt0[(wv * 32) * 32]);
            GLD16(Bh + gb2, &Bt0[(wv * 32 + 16) * 32]);
            GLD16(Bl + gb,  &Bt1[(wv * 32) * 32]);
            GLD16(Bl + gb2, &Bt1[(wv * 32 + 16) * 32]);
        }
        __syncthreads();

        bf16x8 a0[4], a1[4], b0[4], b1[4];
#pragma unroll
        for (int i = 0; i < 4; ++i) {
            a0[i] = *(const bf16x8*)&At0[(mw + i * 16 + lrow) * 32 + qsw];
            a1[i] = *(const bf16x8*)&At1[(mw + i * 16 + lrow) * 32 + qsw];
            b0[i] = *(const bf16x8*)&Bt0[(nw + i * 16 + lrow) * 32 + qsw];
            b1[i] = *(const bf16x8*)&Bt1[(nw + i * 16 + lrow) * 32 + qsw];
        }
#pragma unroll
        for (int mi = 0; mi < 4; ++mi)
#pragma unroll
            for (int nj = 0; nj < 4; ++nj) {
                acc[mi][nj] = __builtin_amdgcn_mfma_f32_16x16x32_bf16(a0[mi], b0[nj], acc[mi][nj], 0, 0, 0);
                acc[mi][nj] = __builtin_amdgcn_mfma_f32_16x16x32_bf16(a0[mi], b1[nj], acc[mi][nj], 0, 0, 0);
                acc[mi][nj] = __builtin_amdgcn_mfma_f32_16x16x32_bf16(a1[mi], b0[nj], acc[mi][nj], 0, 0, 0);
            }
        __syncthreads();
    }

#pragma unroll
    for (int mi = 0; mi < 4; ++mi) {
        const int row = m0 + mw + mi * 16 + quad * 4;
#pragma unroll
        for (int nj = 0; nj < 4; ++nj) {
            const int col = n0 + nw + nj * 16 + lrow;
            const float bv = bias[col];
#pragma unroll
            for (int r = 0; r < 4; ++r)
                C[(size_t)(row + r) * Nn + col] = acc[mi][nj][r] + bv;
        }
    }
}

// ---------------------------------------------------------------------------
// M=4 GEMV for the control path
// ---------------------------------------------------------------------------
__device__ __forceinline__ float gelu_f(float x) {
    return 0.5f * x * (1.f + tanhf(0.7978845608028654f * (x + 0.044715f * x * x * x)));
}

__global__ __launch_bounds__(256) void kern_gemv4(const float* __restrict__ A,
                                                  const float* __restrict__ W,
                                                  const float* __restrict__ bias,
                                                  float* __restrict__ C,
                                                  int Nn, int act) {
    const int tid = threadIdx.x;
    const int wv = tid >> 6, lane = tid & 63;
    const int col = blockIdx.x * 4 + wv;
    const float* wp = W + (size_t)col * D_;
    float a0 = 0.f, a1 = 0.f, a2 = 0.f, a3 = 0.f;
#pragma unroll
    for (int i = 0; i < 16; ++i) {
        int k = lane + i * 64;
        float w = wp[k];
        a0 += A[k] * w;
        a1 += A[D_ + k] * w;
        a2 += A[2 * D_ + k] * w;
        a3 += A[3 * D_ + k] * w;
    }
    for (int m = 1; m < 64; m <<= 1) {
        a0 += __shfl_xor(a0, m);
        a1 += __shfl_xor(a1, m);
        a2 += __shfl_xor(a2, m);
        a3 += __shfl_xor(a3, m);
    }
    if (lane == 0) {
        float bv = bias[col];
        float v0 = a0 + bv, v1 = a1 + bv, v2 = a2 + bv, v3 = a3 + bv;
        if (act) { v0 = gelu_f(v0); v1 = gelu_f(v1); v2 = gelu_f(v2); v3 = gelu_f(v3); }
        C[0 * Nn + col] = v0;
        C[1 * Nn + col] = v1;
        C[2 * Nn + col] = v2;
        C[3 * Nn + col] = v3;
    }
}

// ---------------------------------------------------------------------------
// Featuremap + field build — R8: MFMA MLPs with 3-term split (fp32-grade).
// Geometry identical to R7 (verified by its near-pass); precision upgraded:
// activations & weights split h+m+l (24 mantissa bits, repr err ~2^-27);
// 6 products hh,hm,mh,hl,mm,lh per k-step (dropped terms <= 3*2^-27).
// LDS = 48 KB (3 planes x 8 KB x 2 buffers); 3 blocks/CU.
// ---------------------------------------------------------------------------
#define SWU(r, c) ((r) * 64 + ((((c) >> 3) ^ ((r) & 7)) << 3) + ((c) & 7))
#define SWF(r, c) ((r) * 64 + ((c) ^ (((r) & 7) << 2)))

__global__ __launch_bounds__(256) void kern_feat(float* __restrict__ qkvg,
                                                 const ushort_t* __restrict__ Wfh,
                                                 const ushort_t* __restrict__ Wfm,
                                                 const ushort_t* __restrict__ Wfl,
                                                 const float* __restrict__ qfm_b,
                                                 const float* __restrict__ kfm_b,
                                                 const float* __restrict__ wg_w,
                                                 const float* __restrict__ wg_b,
                                                 float* __restrict__ field) {
    __shared__ __align__(16) ushort_t bufA[3][64 * 64];   // h, m, l planes
    __shared__ __align__(16) ushort_t bufB[3][64 * 64];
    float* bufAf = (float*)bufA;   // fp32 overlay (phi_k) — spans planes 0-1
    float* bufBf = (float*)bufB;   // fp32 overlay (V)

    const int tid = threadIdx.x;
    const int lane = tid & 63, wv = tid >> 6;
    const int quad = lane >> 4, lrow = lane & 15;
    const int mw = (wv >> 1) * 32, nw = (wv & 1) * 32;
    const int n0 = blockIdx.x * 64;
    const int h = blockIdx.y, b = blockIdx.z;
    const size_t rowbase = (size_t)(b * N_ + n0) * 4096;

    const int lr4 = tid >> 4;          // 0..15 row within 16-row group
    const int lc4 = (tid & 15) * 4;    // 0,4,...,60 col

    // load 64x64 fp32 tile from qkvg, 3-term split to bf16 LDS (swizzled)
#define LOADSPLIT3(off, dst) \
    for (int it = 0; it < 4; ++it) { \
        int r = lr4 + it * 16; \
        float4 v4 = *(const float4*)&qkvg[rowbase + (size_t)r * 4096 + (off) + lc4]; \
        ushort_t h0, m0, l0, h1, m1, l1, h2, m2, l2, h3, m3, l3; \
        split3_bf16(v4.x, h0, m0, l0); split3_bf16(v4.y, h1, m1, l1); \
        split3_bf16(v4.z, h2, m2, l2); split3_bf16(v4.w, h3, m3, l3); \
        int ix = SWU(r, lc4); \
        *(uint2*)&(dst)[0][ix] = make_uint2((unsigned)h0 | ((unsigned)h1 << 16), \
                                            (unsigned)h2 | ((unsigned)h3 << 16)); \
        *(uint2*)&(dst)[1][ix] = make_uint2((unsigned)m0 | ((unsigned)m1 << 16), \
                                            (unsigned)m2 | ((unsigned)m3 << 16)); \
        *(uint2*)&(dst)[2][ix] = make_uint2((unsigned)l0 | ((unsigned)l1 << 16), \
                                            (unsigned)l2 | ((unsigned)l3 << 16)); \
    }

    // one MLP layer: acc[2][2] += src @ W[wm]^T (3-term split, 6 products)
#define MLP_MFMA3(src, wm, acc) \
    _Pragma("unroll") for (int ks = 0; ks < 2; ++ks) { \
        bf16x8 a0[2], a1[2], a2[2], b0[2], b1[2], b2[2]; \
        _Pragma("unroll") for (int mt = 0; mt < 2; ++mt) { \
            int ar = mw + mt * 16 + lrow; \
            int ix = ar * 64 + (((ks * 4 + quad) ^ (ar & 7)) << 3); \
            a0[mt] = *(const bf16x8*)&(src)[0][ix]; \
            a1[mt] = *(const bf16x8*)&(src)[1][ix]; \
            a2[mt] = *(const bf16x8*)&(src)[2][ix]; \
        } \
        _Pragma("unroll") for (int nt = 0; nt < 2; ++nt) { \
            int br = nw + nt * 16 + lrow; \
            int ixw = (wm) * 4096 + br * 64 + ks * 32 + quad * 8; \
            b0[nt] = *(const bf16x8*)&Wfh[ixw]; \
            b1[nt] = *(const bf16x8*)&Wfm[ixw]; \
            b2[nt] = *(const bf16x8*)&Wfl[ixw]; \
        } \
        _Pragma("unroll") for (int mt = 0; mt < 2; ++mt) \
        _Pragma("unroll") for (int nt = 0; nt < 2; ++nt) { \
            acc[mt][nt] = __builtin_amdgcn_mfma_f32_16x16x32_bf16(a0[mt], b0[nt], acc[mt][nt], 0, 0, 0); \
            acc[mt][nt] = __builtin_amdgcn_mfma_f32_16x16x32_bf16(a0[mt], b1[nt], acc[mt][nt], 0, 0, 0); \
            acc[mt][nt] = __builtin_amdgcn_mfma_f32_16x16x32_bf16(a1[mt], b0[nt], acc[mt][nt], 0, 0, 0); \
            acc[mt][nt] = __builtin_amdgcn_mfma_f32_16x16x32_bf16(a0[mt], b2[nt], acc[mt][nt], 0, 0, 0); \
            acc[mt][nt] = __builtin_amdgcn_mfma_f32_16x16x32_bf16(a1[mt], b1[nt], acc[mt][nt], 0, 0, 0); \
            acc[mt][nt] = __builtin_amdgcn_mfma_f32_16x16x32_bf16(a2[mt], b0[nt], acc[mt][nt], 0, 0, 0); \
        } \
    }

    // epilogue: bias+relu, 3-term re-split to LDS (for next layer)
#define EPI_SPLIT3(acc, biasp, dst) \
    _Pragma("unroll") for (int mt = 0; mt < 2; ++mt) \
    _Pragma("unroll") for (int nt = 0; nt < 2; ++nt) { \
        int col = nw + nt * 16 + lrow; \
        float bv = (biasp)[col]; \
        _Pragma("unroll") for (int r = 0; r < 4; ++r) { \
            int row = mw + mt * 16 + quad * 4 + r; \
            float v = fmaxf(acc[mt][nt][r] + bv, 0.f); \
            ushort_t hh, mm, ll; split3_bf16(v, hh, mm, ll); \
            int ix = SWU(row, col); \
            (dst)[0][ix] = hh; (dst)[1][ix] = mm; (dst)[2][ix] = ll; \
        } }

    // ============ K path ============
    LOADSPLIT3(D_ + h * 64, bufA)
    __syncthreads();

    // wg for own lane, reconstructed h+m+l (repr err ~2^-27)
    float wgv;
    {
        float s = 0.f;
#pragma unroll
        for (int c8 = 0; c8 < 8; ++c8) {
            int ix = lane * 64 + ((c8 ^ (lane & 7)) << 3);
#pragma unroll
            for (int half = 0; half < 2; ++half) {
                uint2 uh = *(const uint2*)&bufA[0][ix + half * 4];
                uint2 um = *(const uint2*)&bufA[1][ix + half * 4];
                uint2 ul = *(const uint2*)&bufA[2][ix + half * 4];
                unsigned hw[4] = { uh.x & 0xffffu, uh.x >> 16, uh.y & 0xffffu, uh.y >> 16 };
                unsigned mw_[4] = { um.x & 0xffffu, um.x >> 16, um.y & 0xffffu, um.y >> 16 };
                unsigned lw[4] = { ul.x & 0xffffu, ul.x >> 16, ul.y & 0xffffu, ul.y >> 16 };
#pragma unroll
                for (int e = 0; e < 4; ++e) {
                    float kv = __uint_as_float(hw[e] << 16) + __uint_as_float(mw_[e] << 16)
                             + __uint_as_float(lw[e] << 16);
                    s += kv * wg_w[c8 * 8 + half * 4 + e];
                }
            }
        }
        s += wg_b[0];
        wgv = 1.f / (1.f + expf(-s));
    }
    float wg63 = __shfl(wgv, 63);

    {   // K L1 -> bufB (3-term split)
        f32x4 acc[2][2] = {};
        MLP_MFMA3(bufA, 2, acc)
        EPI_SPLIT3(acc, kfm_b, bufB)
    }
    __syncthreads();
    {   // K L2 -> phi_k fp32 into bufAf
        f32x4 acc[2][2] = {};
        MLP_MFMA3(bufB, 3, acc)
#pragma unroll
        for (int mt = 0; mt < 2; ++mt)
#pragma unroll
        for (int nt = 0; nt < 2; ++nt) {
            int col = nw + nt * 16 + lrow;
            float bv = kfm_b[64 + col];
#pragma unroll
            for (int r = 0; r < 4; ++r) {
                int row = mw + mt * 16 + quad * 4 + r;
                bufAf[SWF(row, col)] = fmaxf(acc[mt][nt][r] + bv, 0.f) + EPS_;
            }
        }
    }
    __syncthreads();
    // V -> bufBf (fp32, swizzled)
    for (int it = 0; it < 4; ++it) {
        int r = lr4 + it * 16;
        float4 v4 = *(const float4*)&qkvg[rowbase + (size_t)r * 4096 + 2 * D_ + h * 64 + lc4];
        *(f32x4*)&bufBf[SWF(r, lc4)] = *(f32x4*)&v4;
    }
    __syncthreads();

    // field write: write[c<64] = wg*pk*v ; write[c>=64] = wg*pk
    {
        float* frow = field + (size_t)(b * H_ + h) * 128 * F_;
        const bool last = (n0 == N_ - 64);
        for (int c = wv; c < 128; c += 4) {
            int i = lane;
            float v = (c < 64) ? wgv * bufAf[SWF(i, c)] * bufBf[SWF(i, c)]
                               : wgv * bufAf[SWF(i, c - 64)];
            if (last) {
                if (i == 62) {
                    float v2 = (c < 64) ? wg63 * bufAf[SWF(63, c)] * bufBf[SWF(63, c)]
                                        : wg63 * bufAf[SWF(63, c - 64)];
                    v += v2;
                } else if (i == 63) v = 0.f;
            }
            frow[(size_t)c * F_ + n0 + i] = v;
        }
    }
    __syncthreads();

    // ============ Q path ============
    LOADSPLIT3(h * 64, bufA)
    __syncthreads();
    {   // Q L1 -> bufB
        f32x4 acc[2][2] = {};
        MLP_MFMA3(bufA, 0, acc)
        EPI_SPLIT3(acc, qfm_b, bufB)
    }
    __syncthreads();
    {   // Q L2 -> phi_q fp32 straight to qkvg k-columns
        f32x4 acc[2][2] = {};
        MLP_MFMA3(bufB, 1, acc)
#pragma unroll
        for (int mt = 0; mt < 2; ++mt)
#pragma unroll
        for (int nt = 0; nt < 2; ++nt) {
            int col = nw + nt * 16 + lrow;
            float bv = qfm_b[64 + col];
#pragma unroll
            for (int r = 0; r < 4; ++r) {
                int row = mw + mt * 16 + quad * 4 + r;
                qkvg[rowbase + (size_t)row * 4096 + D_ + h * 64 + col] =
                    fmaxf(acc[mt][nt][r] + bv, 0.f) + EPS_;
            }
        }
    }
#undef LOADSPLIT3
#undef MLP_MFMA3
#undef EPI_SPLIT3
}

// ---------------------------------------------------------------------------
// LayerNorm of q token 0 -> q0n (B x 1024).
// ---------------------------------------------------------------------------
__global__ void kern_ln(const float* __restrict__ qkvg,
                        const float* __restrict__ ln_g,
                        const float* __restrict__ ln_b,
                        float* __restrict__ q0n) {
    const int bh = blockIdx.x, c = threadIdx.x;
    const int b = bh >> 4, h = bh & 15;
    float x = qkvg[(size_t)(b * N_) * 4096 + h * 64 + c];
    float mu = x;
    for (int m = 1; m < 64; m <<= 1) mu += __shfl_xor(mu, m);
    mu *= (1.f / 64.f);
    float dv = (x - mu) * (x - mu);
    for (int m = 1; m < 64; m <<= 1) dv += __shfl_xor(dv, m);
    float var = dv * (1.f / 64.f);
    q0n[b * 1024 + h * 64 + c] = (x - mu) * rsqrtf(var + 1e-5f) * ln_g[c] + ln_b[c];
}

// ---------------------------------------------------------------------------
// Templated table-driven radix-2 FFT helpers (used by kern_prep).
// ---------------------------------------------------------------------------
template <int NT>
__device__ __forceinline__ void fft_fwd_dif_t(float* xr, float* xi, int tid, int logn,
                                              const float2* __restrict__ twid) {
    const int nb = 1 << (logn - 1);
    for (int lh = logn - 1; lh >= 0; --lh) {
        const int hh = 1 << lh;
        const float2* tws = twid + lh * 4096;
        for (int t = tid; t < nb; t += NT) {
            int j = t & (hh - 1);
            int i1 = ((t >> lh) << (lh + 1)) | j;
            int i2 = i1 + hh;
            float2 tw = tws[t];
            float ar = xr[i1], ai = xi[i1];
            float br = xr[i2], bi = xi[i2];
            xr[i1] = ar + br; xi[i1] = ai + bi;
            float tr = ar - br, ti = ai - bi;
            xr[i2] = tr * tw.x - ti * tw.y;
            xi[i2] = tr * tw.y + ti * tw.x;
        }
        __syncthreads();
    }
}

template <int NT>
__device__ __forceinline__ void fft_inv_dit_t(float* xr, float* xi, int tid, int logn,
                                              const float2* __restrict__ twid) {
    const int nb = 1 << (logn - 1);
    for (int lh = 0; lh < logn; ++lh) {
        const int hh = 1 << lh;
        const float2* tws = twid + lh * 4096;
        for (int t = tid; t < nb; t += NT) {
            int j = t & (hh - 1);
            int i1 = ((t >> lh) << (lh + 1)) | j;
            int i2 = i1 + hh;
            float2 tw = tws[t];   // conj applied
            float br = xr[i2], bi = xi[i2];
            float tr = br * tw.x + bi * tw.y;
            float ti = bi * tw.x - br * tw.y;
            float ar = xr[i1], ai = xi[i1];
            xr[i1] = ar + tr; xi[i1] = ai + ti;
            xr[i2] = ar - tr; xi[i2] = ai - ti;
        }
        __syncthreads();
    }
}

// Padded LDS indexing for kern_prep's radix-4 helper (R2).
#define ZIDX(i) ((i) + ((i) >> 4))

// Generic radix-4 fwd stage range [SBEG, SEND) — used by kern_prep only.
template <int NT, int SBEG, int SEND>
__device__ __forceinline__ void fft4_fwd_stages(float2* z, int tid,
                                                const float2* __restrict__ tw4) {
#pragma unroll
    for (int s = SBEG; s < SEND; ++s) {
        const int q = 1024 >> (2 * s);
        const int qq = q + (q >> 4);
        const float2* tws = tw4 + s * 3072;
        for (int t = tid; t < 1024; t += NT) {
            int j = t & (q - 1);
            int base = ((t & ~(q - 1)) << 2) | j;
            int i0, i1, i2, i3;
            if (q >= 16) { i0 = ZIDX(base); i1 = i0 + qq; i2 = i1 + qq; i3 = i2 + qq; }
            else { i0 = ZIDX(base); i1 = ZIDX(base + q); i2 = ZIDX(base + 2 * q); i3 = ZIDX(base + 3 * q); }
            float2 a = z[i0], b = z[i1], c = z[i2], d = z[i3];
            float2 s0 = make_float2(a.x + c.x, a.y + c.y);
            float2 s1 = make_float2(a.x - c.x, a.y - c.y);
            float2 s2 = make_float2(b.x + d.x, b.y + d.y);
            float2 s3 = make_float2(b.x - d.x, b.y - d.y);
            float2 m1 = make_float2(s1.x + s3.y, s1.y - s3.x);
            float2 m2 = make_float2(s0.x - s2.x, s0.y - s2.y);
            float2 m3 = make_float2(s1.x - s3.y, s1.y + s3.x);
            z[i0] = make_float2(s0.x + s2.x, s0.y + s2.y);
            z[i1] = cmul(m1, tws[3 * j + 0]);
            z[i2] = cmul(m2, tws[3 * j + 1]);
            z[i3] = cmul(m3, tws[3 * j + 2]);
        }
        __syncthreads();
    }
}

// ---------------------------------------------------------------------------
// Register radix-4 butterflies for the fused conv4 (R5). Bit-exact math.
// ---------------------------------------------------------------------------
__device__ __forceinline__ void bf4_fwd(float2& e0, float2& e1, float2& e2, float2& e3,
                                        const float2* __restrict__ tws, int j) {
    float2 a = e0, b = e1, c = e2, d = e3;
    float2 s0 = make_float2(a.x + c.x, a.y + c.y);
    float2 s1 = make_float2(a.x - c.x, a.y - c.y);
    float2 s2 = make_float2(b.x + d.x, b.y + d.y);
    float2 s3 = make_float2(b.x - d.x, b.y - d.y);
    float2 m1 = make_float2(s1.x + s3.y, s1.y - s3.x);
    float2 m2 = make_float2(s0.x - s2.x, s0.y - s2.y);
    float2 m3 = make_float2(s1.x - s3.y, s1.y + s3.x);
    e0 = make_float2(s0.x + s2.x, s0.y + s2.y);
    e1 = cmul(m1, tws[3 * j + 0]);
    e2 = cmul(m2, tws[3 * j + 1]);
    e3 = cmul(m3, tws[3 * j + 2]);
}
__device__ __forceinline__ void bf4_fwd_id(float2& e0, float2& e1, float2& e2, float2& e3) {
    float2 a = e0, b = e1, c = e2, d = e3;
    float2 s0 = make_float2(a.x + c.x, a.y + c.y);
    float2 s1 = make_float2(a.x - c.x, a.y - c.y);
    float2 s2 = make_float2(b.x + d.x, b.y + d.y);
    float2 s3 = make_float2(b.x - d.x, b.y - d.y);
    e0 = make_float2(s0.x + s2.x, s0.y + s2.y);
    e1 = make_float2(s1.x + s3.y, s1.y - s3.x);
    e2 = make_float2(s0.x - s2.x, s0.y - s2.y);
    e3 = make_float2(s1.x - s3.y, s1.y + s3.x);
}
__device__ __forceinline__ void bf4_inv(float2& e0, float2& e1, float2& e2, float2& e3,
                                        const float2* __restrict__ tws, int j) {
    float2 a = e0;
    float2 b = cmulc(e1, tws[3 * j + 0]);
    float2 c = cmulc(e2, tws[3 * j + 1]);
    float2 d = cmulc(e3, tws[3 * j + 2]);
    float2 p0 = make_float2(a.x + c.x, a.y + c.y);
    float2 p1 = make_float2(a.x - c.x, a.y - c.y);
    float2 p2 = make_float2(b.x + d.x, b.y + d.y);
    float2 p3 = make_float2(b.x - d.x, b.y - d.y);
    e0 = make_float2(p0.x + p2.x, p0.y + p2.y);
    e1 = make_float2(p1.x - p3.y, p1.y + p3.x);
    e2 = make_float2(p0.x - p2.x, p0.y - p2.y);
    e3 = make_float2(p1.x + p3.y, p1.y - p3.x);
}
__device__ __forceinline__ void bf4_inv_id(float2& e0, float2& e1, float2& e2, float2& e3) {
    float2 a = e0, b = e1, c = e2, d = e3;
    float2 p0 = make_float2(a.x + c.x, a.y + c.y);
    float2 p1 = make_float2(a.x - c.x, a.y - c.y);
    float2 p2 = make_float2(b.x + d.x, b.y + d.y);
    float2 p3 = make_float2(b.x - d.x, b.y - d.y);
    e0 = make_float2(p0.x + p2.x, p0.y + p2.y);
    e1 = make_float2(p1.x - p3.y, p1.y + p3.x);
    e2 = make_float2(p0.x - p2.x, p0.y - p2.y);
    e3 = make_float2(p1.x + p3.y, p1.y - p3.x);
}

// ---------------------------------------------------------------------------
// Merged prep (1024 threads, per (b,h)): build damped-cosine kernel, fwd 8192
// FFT, apply gate in BR order, inv FFT, fold to 4096, radix-4 fwd -> GBR.
// Final radix-4 stage fused into the GBR store, 1/4096 scale folded in.
// ---------------------------------------------------------------------------
__global__ __launch_bounds__(1024) void kern_prep(const float* __restrict__ freq,
                                                  const float* __restrict__ damp,
                                                  const float* __restrict__ phase,
                                                  const float* __restrict__ ctrl,
                                                  const float2* __restrict__ twid,
                                                  const float2* __restrict__ tw4,
                                                  float* __restrict__ GBR) {
    __shared__ float sm[2 * PAD_];    // 64 KB
    float* xr = sm;
    float* xi = sm + PAD_;
    const int bh = blockIdx.x, tid = threadIdx.x;
    const int b = bh >> 4, h = bh & 15;

    // build kernel in time domain
    const float fr = freq[h], ed = expf(damp[h]), ph = phase[h];
    for (int f = tid; f < PAD_; f += 1024) {
        float v = 0.f;
        if (f < F_) {
            float t = (float)f / (float)F_;
            v = expf(-ed * t) * cosf(fr * t + ph);
        }
        xr[f] = v; xi[f] = 0.f;
    }
    __syncthreads();
    fft_fwd_dif_t<1024>(xr, xi, tid, 13, twid);   // natural -> BR spectrum

    // gate in BR order
    const float* cp = ctrl + b * (H_ * NC_) + h * NC_;
    for (int j = tid; j < PAD_; j += 1024) {
        int k = (int)(__brev((unsigned)j) >> 19);
        int kk = min(k, PAD_ - k);
        float ip = (float)kk * ((float)(NC_ - 1) / (float)(FB_ - 1));
        int il = min((int)ip, NC_ - 2);
        float iw = ip - (float)il;
        float m = 1.f + cp[il] * (1.f - iw) + cp[il + 1] * iw;
        xr[j] *= m;
        xi[j] *= m;
    }
    __syncthreads();
    fft_inv_dit_t<1024>(xr, xi, tid, 13, twid);   // BR -> natural keff (unscaled)

    // fold to 4096 real kernel, staged through registers
    float g[4];
    const float sc = 1.f / (float)PAD_;
#pragma unroll
    for (int u = 0; u < 4; ++u) {
        int j = tid + u * 1024;
        g[u] = ((j < 2048) ? xr[j] : xr[j + 4096]) * sc;
    }
    __syncthreads();
    float2* z = (float2*)sm;
#pragma unroll
    for (int u = 0; u < 4; ++u) {
        int j = tid + u * 1024;
        z[ZIDX(j)] = make_float2(g[u], 0.f);
    }
    __syncthreads();
    fft4_fwd_stages<1024, 0, 5>(z, tid, tw4);     // stages 0..4
    // fused final stage (q=1, identity twiddles) -> GBR global, scaled 1/4096
    {
        const float sc2 = 1.f / 4096.f;
        const int t = tid;   // 1024 threads, one butterfly each
        const int base = t << 2;
        float2 a = z[ZIDX(base)], bq = z[ZIDX(base + 1)];
        float2 c = z[ZIDX(base + 2)], dq = z[ZIDX(base + 3)];
        float2 s0 = make_float2(a.x + c.x, a.y + c.y);
        float2 s1 = make_float2(a.x - c.x, a.y - c.y);
        float2 s2 = make_float2(bq.x + dq.x, bq.y + dq.y);
        float2 s3 = make_float2(bq.x - dq.x, bq.y - dq.y);
        float2 o0 = make_float2(s0.x + s2.x, s0.y + s2.y);
        float2 o1 = make_float2(s1.x + s3.y, s1.y - s3.x);
        float2 o2 = make_float2(s0.x - s2.x, s0.y - s2.y);
        float2 o3 = make_float2(s1.x - s3.y, s1.y + s3.x);
        float2* Gp = (float2*)GBR + (size_t)bh * 4096 + base;
        Gp[0] = make_float2(o0.x * sc2, o0.y * sc2);
        Gp[1] = make_float2(o1.x * sc2, o1.y * sc2);
        Gp[2] = make_float2(o2.x * sc2, o2.y * sc2);
        Gp[3] = make_float2(o3.x * sc2, o3.y * sc2);
    }
}

// ---------------------------------------------------------------------------
// Main conv (R5): register-fused double stages, 5 LDS passes, 4 barriers.
// ---------------------------------------------------------------------------
#define LIDX(i) ((i) ^ (((i) >> 4) & 15))

__global__ __launch_bounds__(256) void kern_conv4(float* __restrict__ field,
                                                  const float* __restrict__ GBR,
                                                  const float2* __restrict__ tw4) {
    __shared__ float2 z[4096];
    const int tid = threadIdx.x;
    const int bh = blockIdx.x >> 6, cp = blockIdx.x & 63;
    float* rowx = field + ((size_t)bh * 128 + 2 * cp) * F_;
    float* rowy = rowx + F_;
    const float2* tws0 = tw4;
    const float2* tws1 = tw4 + 3072;
    const float2* tws2 = tw4 + 2 * 3072;
    const float2* tws3 = tw4 + 3 * 3072;
    const float2* tws4s = tw4 + 4 * 3072;

    float2 x[16];

    // ---- P1: load + fwd stages 0 (q=1024), 1 (q=256) ----
    {
        const int j16 = tid;
#pragma unroll
        for (int m = 0; m < 8; ++m)
            x[m] = make_float2(rowx[j16 + 256 * m], rowy[j16 + 256 * m]);
#pragma unroll
        for (int m = 8; m < 16; ++m) x[m] = make_float2(0.f, 0.f);
#pragma unroll
        for (int r = 0; r < 4; ++r)
            bf4_fwd(x[r], x[r + 4], x[r + 8], x[r + 12], tws0, j16 + 256 * r);
#pragma unroll
        for (int c = 0; c < 4; ++c)
            bf4_fwd(x[4 * c], x[4 * c + 1], x[4 * c + 2], x[4 * c + 3], tws1, j16);
#pragma unroll
        for (int m = 0; m < 16; ++m) z[LIDX(j16 + 256 * m)] = x[m];
    }
    __syncthreads();

    // ---- P2: fwd stages 2 (q=64), 3 (q=16) ----
    {
        const int j16 = tid & 15;
        const int pb = (tid >> 4) * 256 + j16;
#pragma unroll
        for (int m = 0; m < 16; ++m) x[m] = z[LIDX(pb + 16 * m)];
#pragma unroll
        for (int r = 0; r < 4; ++r)
            bf4_fwd(x[r], x[r + 4], x[r + 8], x[r + 12], tws2, j16 + 16 * r);
#pragma unroll
        for (int c = 0; c < 4; ++c)
            bf4_fwd(x[4 * c], x[4 * c + 1], x[4 * c + 2], x[4 * c + 3], tws3, j16);
#pragma unroll
        for (int m = 0; m < 16; ++m) z[LIDX(pb + 16 * m)] = x[m];
    }
    __syncthreads();

    // ---- P3: fwd stages 4 (q=4), 5 (q=1,id) + G + inv 5 (id), 4 ----
    {
        const int pb = tid * 16;
#pragma unroll
        for (int m = 0; m < 16; ++m) x[m] = z[LIDX(pb + m)];
#pragma unroll
        for (int r = 0; r < 4; ++r)
            bf4_fwd(x[r], x[r + 4], x[r + 8], x[r + 12], tws4s, r);
#pragma unroll
        for (int c = 0; c < 4; ++c)
            bf4_fwd_id(x[4 * c], x[4 * c + 1], x[4 * c + 2], x[4 * c + 3]);
        const float2* G = (const float2*)GBR + (size_t)bh * 4096 + pb;
#pragma unroll
        for (int m = 0; m < 16; ++m) x[m] = cmul(x[m], G[m]);
#pragma unroll
        for (int c = 0; c < 4; ++c)
            bf4_inv_id(x[4 * c], x[4 * c + 1], x[4 * c + 2], x[4 * c + 3]);
#pragma unroll
        for (int r = 0; r < 4; ++r)
            bf4_inv(x[r], x[r + 4], x[r + 8], x[r + 12], tws4s, r);
#pragma unroll
        for (int m = 0; m < 16; ++m) z[LIDX(pb + m)] = x[m];
    }
    __syncthreads();

    // ---- P4: inv stages 3 (q=16), 2 (q=64) ----
    {
        const int j16 = tid & 15;
        const int pb = (tid >> 4) * 256 + j16;
#pragma unroll
        for (int m = 0; m < 16; ++m) x[m] = z[LIDX(pb + 16 * m)];
#pragma unroll
        for (int c = 0; c < 4; ++c)
            bf4_inv(x[4 * c], x[4 * c + 1], x[4 * c + 2], x[4 * c + 3], tws3, j16);
#pragma unroll
        for (int r = 0; r < 4; ++r)
            bf4_inv(x[r], x[r + 4], x[r + 8], x[r + 12], tws2, j16 + 16 * r);
#pragma unroll
        for (int m = 0; m < 16; ++m) z[LIDX(pb + 16 * m)] = x[m];
    }
    __syncthreads();

    // ---- P5: inv stages 1 (q=256), 0 (q=1024) + store (p < 2048) ----
    {
        const int j16 = tid;
#pragma unroll
        for (int m = 0; m < 16; ++m) x[m] = z[LIDX(j16 + 256 * m)];
#pragma unroll
        for (int c = 0; c < 4; ++c)
            bf4_inv(x[4 * c], x[4 * c + 1], x[4 * c + 2], x[4 * c + 3], tws1, j16);
#pragma unroll
        for (int r = 0; r < 4; ++r)
            bf4_inv(x[r], x[r + 4], x[r + 8], x[r + 12], tws0, j16 + 256 * r);
#pragma unroll
        for (int m = 0; m < 8; ++m) {
            rowx[j16 + 256 * m] = x[m].x;
            rowy[j16 + 256 * m] = x[m].y;
        }
    }
}

// ---------------------------------------------------------------------------
// combine (LDS-staged g-plane gather from R2).
// ---------------------------------------------------------------------------
__global__ __launch_bounds__(1024) void kern_combine(float* __restrict__ qkvg,
                                                     const float* __restrict__ field,
                                                     const float* __restrict__ coupling) {
    __shared__ float cpl[16][16];
    __shared__ float sbuf[2][128][17];
    const int tid = threadIdx.x;
    if (tid < 256) cpl[tid >> 4][tid & 15] = coupling[tid];
    const int lane = tid & 63, wv = tid >> 6;
    const int n = blockIdx.x * 16 + wv;
    const int b = blockIdx.y;
    const int f0 = blockIdx.x * 16;
    const int fi = min(n, F_ - 2) - f0;   // 0..15 (last block: clamped to 14)
    const size_t row = (size_t)(b * N_ + n) * 4096;

    // loader role: c = tid>>3 (0..127), k = (tid&7)*2
    const int lc = tid >> 3, lk = (tid & 7) * 2;
    const float* fb = field + (size_t)b * 16 * 128 * F_;

    float2 rv = *(const float2*)&fb[(size_t)lc * F_ + f0 + lk];   // slice g=0
    __syncthreads();                       // cpl visible before any reads
    sbuf[0][lc][lk] = rv.x; sbuf[0][lc][lk + 1] = rv.y;

    float ynum[16], yden[16];
#pragma unroll
    for (int hh = 0; hh < 16; ++hh) { ynum[hh] = 0.f; yden[hh] = 0.f; }

    for (int g = 0; g < 16; ++g) {
        if (g < 15)
            rv = *(const float2*)&fb[((size_t)(g + 1) * 128 + lc) * F_ + f0 + lk];
        __syncthreads();                   // sbuf[g&1] writes done; prior reads of sbuf[(g+1)&1] done
        const float nv = sbuf[g & 1][lane][fi];
        const float dv = sbuf[g & 1][64 + lane][fi];
#pragma unroll
        for (int hh = 0; hh < 16; ++hh) {
            const float cg = cpl[hh][g];
            ynum[hh] += cg * nv;
            yden[hh] += cg * dv;
        }
        if (g < 15) { sbuf[(g + 1) & 1][lc][lk] = rv.x; sbuf[(g + 1) & 1][lc][lk + 1] = rv.y; }
    }

    ushort_t* rp = (ushort_t*)(qkvg + row);
#pragma unroll
    for (int hh = 0; hh < 16; ++hh) {
        float pq = qkvg[row + D_ + hh * 64 + lane];
        float gv = qkvg[row + 3 * D_ + hh * 64 + lane];
        float s = pq * yden[hh];
        for (int m = 1; m < 64; m <<= 1) s += __shfl_xor(s, m);
        float den = fabsf(s) + 1e-4f;
        float o = pq * ynum[hh] / den * (1.f / (1.f + expf(-gv)));
        ushort_t oh, ol;
        split_bf16(o, oh, ol);
        rp[hh * 64 + lane] = oh;
        rp[1024 + hh * 64 + lane] = ol;
    }
}

// ---------------------------------------------------------------------------
extern "C" void kernel_launch(void* const* d_in, const int* in_sizes, int n_in,
                              void* d_out, int out_size, void* d_ws, size_t ws_size,
                              hipStream_t stream) {
    const float* x      = (const float*)d_in[0];
    const float* w_qkvg = (const float*)d_in[1];
    const float* b_qkvg = (const float*)d_in[2];
    const float* w_out  = (const float*)d_in[3];
    const float* b_out  = (const float*)d_in[4];
    const float* qfm_w  = (const float*)d_in[5];
    const float* qfm_b  = (const float*)d_in[6];
    const float* kfm_w  = (const float*)d_in[7];
    const float* kfm_b  = (const float*)d_in[8];
    const float* wg_w   = (const float*)d_in[9];
    const float* wg_b   = (const float*)d_in[10];
    const float* ln_g   = (const float*)d_in[11];
    const float* ln_b   = (const float*)d_in[12];
    const float* sg_w1  = (const float*)d_in[13];
    const float* sg_b1  = (const float*)d_in[14];
    const float* sg_w2  = (const float*)d_in[15];
    const float* sg_b2  = (const float*)d_in[16];
    const float* wfreq  = (const float*)d_in[17];
    const float* wdamp  = (const float*)d_in[18];
    const float* wphase = (const float*)d_in[19];
    const float* coup   = (const float*)d_in[20];

    float* ws = (float*)d_ws;
    // workspace (floats):
    float*  qkvg   = ws;                 // 33,554,432
    float*  field  = ws + 33554432;      // 16,777,216
    float*  GBR    = ws + 50593792;      //    524,288
    float2* twid   = (float2*)(ws + 51118080);   // 106,496 floats (radix-2)
    float*  q0n    = ws + 51224576;      //      4,096
    float*  h1     = ws + 51228672;      //      4,096
    float*  ctrl   = ws + 51232768;      //      2,048
    ushort_t* wouth = (ushort_t*)(ws + 51234816); // 524,288 floats
    ushort_t* woutl = (ushort_t*)(ws + 51759104); // 524,288 floats
    float2* tw4    = (float2*)(ws + 52283392);    // 36,864 floats (radix-4)
    // featmap weights, 3-term bf16 split (3 x 16384 ushort = 96 KB):
    ushort_t* Wfh  = (ushort_t*)(ws + 52320256);
    ushort_t* Wfm  = Wfh + 4 * 4096;
    ushort_t* Wfl  = Wfm + 4 * 4096;
    // end: 52,344,832 floats = 209.4 MB

    // bf16 staging aliases inside `field` (consumed by gemm#1 before feat writes)
    ushort_t* xh  = (ushort_t*)(field);
    ushort_t* xl  = (ushort_t*)(field + 4194304);
    ushort_t* wqh = (ushort_t*)(field + 8388608);
    ushort_t* wql = (ushort_t*)(field + 10485760);

    // 0. twiddles + featmap weight 3-split (merged) + input splits (merged)
    kern_twid<<<(13 * 4096 + 6 * 3072 + 4 * 4096) / 256, 256, 0, stream>>>(
        twid, tw4, qfm_w, kfm_w, Wfh, Wfm, Wfl);
    kern_split3<<<(B_ * N_ * D_ + 4 * D_ * D_ + D_ * D_) / 256, 256, 0, stream>>>(
        x, xh, xl, B_ * N_ * D_,
        w_qkvg, wqh, wql, 4 * D_ * D_,
        w_out, wouth, woutl, D_ * D_);

    // 1. qkvg = x @ w_qkvg^T + b_qkvg   (split-bf16 MFMA; 4 M-slices for
    //    profiler visibility — same total work)
    for (int l = 0; l < 4; ++l) {
        const size_t aoff = (size_t)l * 2048 * D_;
        gemm_mfma<<<dim3(4096 / 128, 2048 / 128), 256, 0, stream>>>(
            xh + aoff, xl + aoff, D_, wqh, wql, D_, b_qkvg,
            qkvg + (size_t)l * 2048 * 4096, 4 * D_, D_);
    }

    // 2. control path: LN + two M=4 GEMVs
    kern_ln<<<B_ * H_, 64, 0, stream>>>(qkvg, ln_g, ln_b, q0n);
    kern_gemv4<<<D_ / 4, 256, 0, stream>>>(q0n, sg_w1, sg_b1, h1, D_, 1);
    kern_gemv4<<<(H_ * NC_) / 4, 256, 0, stream>>>(h1, sg_w2, sg_b2, ctrl, H_ * NC_, 0);

    // 3. spectra prep (merged base FFT + gate + fold, 1024 thr)
    kern_prep<<<B_ * H_, 1024, 0, stream>>>(wfreq, wdamp, wphase, ctrl, twid, tw4, GBR);

    // 4. featmaps + wg + field build (MFMA MLPs, 3-term split weights)
    kern_feat<<<dim3(N_ / 64, H_, B_), 256, 0, stream>>>(
        qkvg, Wfh, Wfm, Wfl, qfm_b, kfm_b, wg_w, wg_b, field);

    // 5. FFT convolution (register-fused radix-16 passes, 256 thr)
    kern_conv4<<<B_ * H_ * 64, 256, 0, stream>>>(field, GBR, tw4);

    // 6. combine (+fused coupling, LDS-staged) -> qkvg q-columns
    kern_combine<<<dim3(N_ / 16, B_), 1024, 0, stream>>>(qkvg, field, coup);

    // 7. out = att @ w_out^T + b_out
    gemm_mfma<<<dim3(1024 / 128, 8192 / 128), 256, 0, stream>>>(
        (ushort_t*)qkvg, (ushort_t*)qkvg + 1024, 8192,
        wouth, woutl, D_, b_out, (float*)d_out, D_, D_);
}

// Round 9
// 673.584 us; speedup vs baseline: 1.0251x; 1.0200x over previous
//
#include <hip/hip_runtime.h>
#include <math.h>

// Problem constants
#define B_   4
#define N_   2048
#define D_   1024
#define H_   16
#define d_   64
#define F_   2048
#define PAD_ 8192
#define FB_  4097
#define NC_  32
#define EPS_ 1e-6f
#define PI_F 3.14159265358979323846f
#define PI_D 3.14159265358979323846

typedef unsigned short ushort_t;
typedef short bf16x8 __attribute__((ext_vector_type(8)));
typedef float f32x4  __attribute__((ext_vector_type(4)));

#define GLD16(gp, lp) __builtin_amdgcn_global_load_lds( \
    (const __attribute__((address_space(1))) unsigned int*)(const void*)(gp), \
    (__attribute__((address_space(3))) unsigned int*)(void*)(lp), 16, 0, 0)

// round-to-nearest-even fp32 -> bf16 (bits), plus residual splits
__device__ __forceinline__ ushort_t bf16_rne(float v) {
    unsigned b = __float_as_uint(v);
    unsigned rb = b + 0x7fffu + ((b >> 16) & 1u);
    return (ushort_t)(rb >> 16);
}
__device__ __forceinline__ void split_bf16(float v, ushort_t& h, ushort_t& l) {
    h = bf16_rne(v);
    float fh = __uint_as_float((unsigned)h << 16);
    l = bf16_rne(v - fh);
}
// 3-term split: v = h + m + l with ~2^-27 relative error (24 mantissa bits)
__device__ __forceinline__ void split3_bf16(float v, ushort_t& h, ushort_t& m, ushort_t& l) {
    h = bf16_rne(v);
    float fh = __uint_as_float((unsigned)h << 16);
    float r = v - fh;
    m = bf16_rne(r);
    float fm = __uint_as_float((unsigned)m << 16);
    l = bf16_rne(r - fm);
}

__device__ __forceinline__ float2 cmul(float2 a, float2 w) {
    return make_float2(a.x * w.x - a.y * w.y, a.x * w.y + a.y * w.x);
}
__device__ __forceinline__ float2 cmulc(float2 a, float2 w) {   // a * conj(w)
    return make_float2(a.x * w.x + a.y * w.y, a.y * w.x - a.x * w.y);
}

// ---------------------------------------------------------------------------
// Merged twiddle builder: radix-2 table (13*4096), radix-4 table (6*3072),
// + featmap weight 3-term bf16 split (original [j][c] layout = K-contiguous
// row layout for MFMA B-frags). mats: 0=qfm L1, 1=qfm L2, 2=kfm L1, 3=kfm L2.
// ---------------------------------------------------------------------------
__global__ __launch_bounds__(256) void kern_twid(float2* __restrict__ twid,
                                                 float2* __restrict__ tw4,
                                                 const float* __restrict__ qfm_w,
                                                 const float* __restrict__ kfm_w,
                                                 ushort_t* __restrict__ Wfh,
                                                 ushort_t* __restrict__ Wfm,
                                                 ushort_t* __restrict__ Wfl) {
    int idx = blockIdx.x * 256 + threadIdx.x;
    if (idx < 13 * 4096) {
        const int lh = idx >> 12, t = idx & 4095;
        const int hh = 1 << lh;
        const int j = t & (hh - 1);
        double s, c;
        sincos(-PI_D * (double)j / (double)hh, &s, &c);
        twid[idx] = make_float2((float)c, (float)s);
    } else {
        idx -= 13 * 4096;
        if (idx < 6 * 3072) {
            const int s = idx / 3072;
            const int r = idx - s * 3072;
            const int j = r / 3;
            const int m = r - 3 * j + 1;
            const int q = 1024 >> (2 * s);
            double sn, cs;
            sincos(-2.0 * PI_D * (double)(m * (j & (q - 1))) / (double)(4 * q), &sn, &cs);
            tw4[idx] = make_float2((float)cs, (float)sn);
        } else {
            idx -= 6 * 3072;
            if (idx < 4 * 4096) {
                const int mat = idx >> 12, e = idx & 4095;
                const float* src = (mat < 2) ? qfm_w : kfm_w;
                float v = src[(mat & 1) * 4096 + e];
                ushort_t hh, mm, ll;
                split3_bf16(v, hh, mm, ll);
                Wfh[mat * 4096 + e] = hh;
                Wfm[mat * 4096 + e] = mm;
                Wfl[mat * 4096 + e] = ll;
            }
        }
    }
}

// ---------------------------------------------------------------------------
// Merged split: three fp32 arrays -> (hi, lo) bf16 arrays in one launch
// ---------------------------------------------------------------------------
__global__ __launch_bounds__(256) void kern_split3(
        const float* __restrict__ s0, ushort_t* __restrict__ h0, ushort_t* __restrict__ l0, int n0,
        const float* __restrict__ s1, ushort_t* __restrict__ h1, ushort_t* __restrict__ l1, int n1,
        const float* __restrict__ s2, ushort_t* __restrict__ h2, ushort_t* __restrict__ l2, int n2) {
    int i = blockIdx.x * 256 + threadIdx.x;
    const float* s; ushort_t* hh; ushort_t* ll; int k;
    if (i < n0)                { s = s0; hh = h0; ll = l0; k = i; }
    else if (i < n0 + n1)      { s = s1; hh = h1; ll = l1; k = i - n0; }
    else if (i < n0 + n1 + n2) { s = s2; hh = h2; ll = l2; k = i - n0 - n1; }
    else return;
    ushort_t h, l;
    split_bf16(s[k], h, l);
    hh[k] = h; ll[k] = l;
}

// ---------------------------------------------------------------------------
// Split-bf16 MFMA NT GEMM: C = A*B^T + bias. 3 cross-products.
// 128x128 tile, BK=32, 256 thr. M, Nn, K multiples of 128.
// R9: gemm1 back to a SINGLE 2048-block launch — R3's 4-slice split ran each
// slice at 2 blocks/CU (below the 3-block LDS capacity) and cost ~100 µs.
// ---------------------------------------------------------------------------
__global__ __launch_bounds__(256) void gemm_mfma(
        const ushort_t* __restrict__ Ah, const ushort_t* __restrict__ Al, int lda,
        const ushort_t* __restrict__ Bh, const ushort_t* __restrict__ Bl, int ldb,
        const float* __restrict__ bias, float* __restrict__ C,
        int Nn, int K) {
    __shared__ __align__(16) ushort_t At0[128 * 32];
    __shared__ __align__(16) ushort_t At1[128 * 32];
    __shared__ __align__(16) ushort_t Bt0[128 * 32];
    __shared__ __align__(16) ushort_t Bt1[128 * 32];

    const int tid = threadIdx.x;
    const int wv = tid >> 6, lane = tid & 63;
    const int quad = lane >> 4, lrow = lane & 15;
    const int m0 = blockIdx.y * 128, n0 = blockIdx.x * 128;
    const int mw = (wv >> 1) * 64, nw = (wv & 1) * 64;

    const int srow = lane >> 2;
    const int schunk = (((lane & 3) ^ ((lane >> 3) & 3)) * 8);
    const int qsw = ((quad ^ ((lrow >> 1) & 3)) * 8);

    f32x4 acc[4][4] = {};

    for (int k0 = 0; k0 < K; k0 += 32) {
        {
            const size_t ga = (size_t)(m0 + wv * 32 + srow) * lda + k0 + schunk;
            const size_t gb = (size_t)(n0 + wv * 32 + srow) * ldb + k0 + schunk;
            const size_t ga2 = ga + (size_t)16 * lda;
            const size_t gb2 = gb + (size_t)16 * ldb;
            GLD16(Ah + ga,  &At0[(wv * 32) * 32]);
            GLD16(Ah + ga2, &At0[(wv * 32 + 16) * 32]);
            GLD16(Al + ga,  &At1[(wv * 32) * 32]);
            GLD16(Al + ga2, &At1[(wv * 32 + 16) * 32]);
            GLD16(Bh + gb,  &Bt0[(wv * 32) * 32]);
            GLD16(Bh + gb2, &Bt0[(wv * 32 + 16) * 32]);
            GLD16(Bl + gb,  &Bt1[(wv * 32) * 32]);
            GLD16(Bl + gb2, &Bt1[(wv * 32 + 16) * 32]);
        }
        __syncthreads();

        bf16x8 a0[4], a1[4], b0[4], b1[4];
#pragma unroll
        for (int i = 0; i < 4; ++i) {
            a0[i] = *(const bf16x8*)&At0[(mw + i * 16 + lrow) * 32 + qsw];
            a1[i] = *(const bf16x8*)&At1[(mw + i * 16 + lrow) * 32 + qsw];
            b0[i] = *(const bf16x8*)&Bt0[(nw + i * 16 + lrow) * 32 + qsw];
            b1[i] = *(const bf16x8*)&Bt1[(nw + i * 16 + lrow) * 32 + qsw];
        }
#pragma unroll
        for (int mi = 0; mi < 4; ++mi)
#pragma unroll
            for (int nj = 0; nj < 4; ++nj) {
                acc[mi][nj] = __builtin_amdgcn_mfma_f32_16x16x32_bf16(a0[mi], b0[nj], acc[mi][nj], 0, 0, 0);
                acc[mi][nj] = __builtin_amdgcn_mfma_f32_16x16x32_bf16(a0[mi], b1[nj], acc[mi][nj], 0, 0, 0);
                acc[mi][nj] = __builtin_amdgcn_mfma_f32_16x16x32_bf16(a1[mi], b0[nj], acc[mi][nj], 0, 0, 0);
            }
        __syncthreads();
    }

#pragma unroll
    for (int mi = 0; mi < 4; ++mi) {
        const int row = m0 + mw + mi * 16 + quad * 4;
#pragma unroll
        for (int nj = 0; nj < 4; ++nj) {
            const int col = n0 + nw + nj * 16 + lrow;
            const float bv = bias[col];
#pragma unroll
            for (int r = 0; r < 4; ++r)
                C[(size_t)(row + r) * Nn + col] = acc[mi][nj][r] + bv;
        }
    }
}

// ---------------------------------------------------------------------------
// M=4 GEMV for the control path
// ---------------------------------------------------------------------------
__device__ __forceinline__ float gelu_f(float x) {
    return 0.5f * x * (1.f + tanhf(0.7978845608028654f * (x + 0.044715f * x * x * x)));
}

__global__ __launch_bounds__(256) void kern_gemv4(const float* __restrict__ A,
                                                  const float* __restrict__ W,
                                                  const float* __restrict__ bias,
                                                  float* __restrict__ C,
                                                  int Nn, int act) {
    const int tid = threadIdx.x;
    const int wv = tid >> 6, lane = tid & 63;
    const int col = blockIdx.x * 4 + wv;
    const float* wp = W + (size_t)col * D_;
    float a0 = 0.f, a1 = 0.f, a2 = 0.f, a3 = 0.f;
#pragma unroll
    for (int i = 0; i < 16; ++i) {
        int k = lane + i * 64;
        float w = wp[k];
        a0 += A[k] * w;
        a1 += A[D_ + k] * w;
        a2 += A[2 * D_ + k] * w;
        a3 += A[3 * D_ + k] * w;
    }
    for (int m = 1; m < 64; m <<= 1) {
        a0 += __shfl_xor(a0, m);
        a1 += __shfl_xor(a1, m);
        a2 += __shfl_xor(a2, m);
        a3 += __shfl_xor(a3, m);
    }
    if (lane == 0) {
        float bv = bias[col];
        float v0 = a0 + bv, v1 = a1 + bv, v2 = a2 + bv, v3 = a3 + bv;
        if (act) { v0 = gelu_f(v0); v1 = gelu_f(v1); v2 = gelu_f(v2); v3 = gelu_f(v3); }
        C[0 * Nn + col] = v0;
        C[1 * Nn + col] = v1;
        C[2 * Nn + col] = v2;
        C[3 * Nn + col] = v3;
    }
}

// ---------------------------------------------------------------------------
// Featuremap + field build — R8 MFMA MLPs (3-term split, fp32-grade) +
// R9: T14 early-issue — V and Q tiles loaded into REGISTERS at kernel start
// so their HBM latency hides under the K-path compute (they were previously
// serial global-load phases between barriers). Values identical.
// ---------------------------------------------------------------------------
#define SWU(r, c) ((r) * 64 + ((((c) >> 3) ^ ((r) & 7)) << 3) + ((c) & 7))
#define SWF(r, c) ((r) * 64 + ((c) ^ (((r) & 7) << 2)))

__global__ __launch_bounds__(256) void kern_feat(float* __restrict__ qkvg,
                                                 const ushort_t* __restrict__ Wfh,
                                                 const ushort_t* __restrict__ Wfm,
                                                 const ushort_t* __restrict__ Wfl,
                                                 const float* __restrict__ qfm_b,
                                                 const float* __restrict__ kfm_b,
                                                 const float* __restrict__ wg_w,
                                                 const float* __restrict__ wg_b,
                                                 float* __restrict__ field) {
    __shared__ __align__(16) ushort_t bufA[3][64 * 64];   // h, m, l planes
    __shared__ __align__(16) ushort_t bufB[3][64 * 64];
    float* bufAf = (float*)bufA;   // fp32 overlay (phi_k) — spans planes 0-1
    float* bufBf = (float*)bufB;   // fp32 overlay (V)

    const int tid = threadIdx.x;
    const int lane = tid & 63, wv = tid >> 6;
    const int quad = lane >> 4, lrow = lane & 15;
    const int mw = (wv >> 1) * 32, nw = (wv & 1) * 32;
    const int n0 = blockIdx.x * 64;
    const int h = blockIdx.y, b = blockIdx.z;
    const size_t rowbase = (size_t)(b * N_ + n0) * 4096;

    const int lr4 = tid >> 4;          // 0..15 row within 16-row group
    const int lc4 = (tid & 15) * 4;    // 0,4,...,60 col

    // T14: issue V and Q tile loads NOW; consumed much later.
    float4 vreg[4], qreg[4];
#pragma unroll
    for (int it = 0; it < 4; ++it) {
        int r = lr4 + it * 16;
        vreg[it] = *(const float4*)&qkvg[rowbase + (size_t)r * 4096 + 2 * D_ + h * 64 + lc4];
        qreg[it] = *(const float4*)&qkvg[rowbase + (size_t)r * 4096 + h * 64 + lc4];
    }

    // load 64x64 fp32 tile from qkvg, 3-term split to bf16 LDS (swizzled)
#define LOADSPLIT3(off, dst) \
    for (int it = 0; it < 4; ++it) { \
        int r = lr4 + it * 16; \
        float4 v4 = *(const float4*)&qkvg[rowbase + (size_t)r * 4096 + (off) + lc4]; \
        ushort_t h0, m0, l0, h1, m1, l1, h2, m2, l2, h3, m3, l3; \
        split3_bf16(v4.x, h0, m0, l0); split3_bf16(v4.y, h1, m1, l1); \
        split3_bf16(v4.z, h2, m2, l2); split3_bf16(v4.w, h3, m3, l3); \
        int ix = SWU(r, lc4); \
        *(uint2*)&(dst)[0][ix] = make_uint2((unsigned)h0 | ((unsigned)h1 << 16), \
                                            (unsigned)h2 | ((unsigned)h3 << 16)); \
        *(uint2*)&(dst)[1][ix] = make_uint2((unsigned)m0 | ((unsigned)m1 << 16), \
                                            (unsigned)m2 | ((unsigned)m3 << 16)); \
        *(uint2*)&(dst)[2][ix] = make_uint2((unsigned)l0 | ((unsigned)l1 << 16), \
                                            (unsigned)l2 | ((unsigned)l3 << 16)); \
    }

    // same, but from a register tile (T14 use-late)
#define SPLITREG3(srcreg, dst) \
    for (int it = 0; it < 4; ++it) { \
        int r = lr4 + it * 16; \
        float4 v4 = srcreg[it]; \
        ushort_t h0, m0, l0, h1, m1, l1, h2, m2, l2, h3, m3, l3; \
        split3_bf16(v4.x, h0, m0, l0); split3_bf16(v4.y, h1, m1, l1); \
        split3_bf16(v4.z, h2, m2, l2); split3_bf16(v4.w, h3, m3, l3); \
        int ix = SWU(r, lc4); \
        *(uint2*)&(dst)[0][ix] = make_uint2((unsigned)h0 | ((unsigned)h1 << 16), \
                                            (unsigned)h2 | ((unsigned)h3 << 16)); \
        *(uint2*)&(dst)[1][ix] = make_uint2((unsigned)m0 | ((unsigned)m1 << 16), \
                                            (unsigned)m2 | ((unsigned)m3 << 16)); \
        *(uint2*)&(dst)[2][ix] = make_uint2((unsigned)l0 | ((unsigned)l1 << 16), \
                                            (unsigned)l2 | ((unsigned)l3 << 16)); \
    }

    // one MLP layer: acc[2][2] += src @ W[wm]^T (3-term split, 6 products)
#define MLP_MFMA3(src, wm, acc) \
    _Pragma("unroll") for (int ks = 0; ks < 2; ++ks) { \
        bf16x8 a0[2], a1[2], a2[2], b0[2], b1[2], b2[2]; \
        _Pragma("unroll") for (int mt = 0; mt < 2; ++mt) { \
            int ar = mw + mt * 16 + lrow; \
            int ix = ar * 64 + (((ks * 4 + quad) ^ (ar & 7)) << 3); \
            a0[mt] = *(const bf16x8*)&(src)[0][ix]; \
            a1[mt] = *(const bf16x8*)&(src)[1][ix]; \
            a2[mt] = *(const bf16x8*)&(src)[2][ix]; \
        } \
        _Pragma("unroll") for (int nt = 0; nt < 2; ++nt) { \
            int br = nw + nt * 16 + lrow; \
            int ixw = (wm) * 4096 + br * 64 + ks * 32 + quad * 8; \
            b0[nt] = *(const bf16x8*)&Wfh[ixw]; \
            b1[nt] = *(const bf16x8*)&Wfm[ixw]; \
            b2[nt] = *(const bf16x8*)&Wfl[ixw]; \
        } \
        _Pragma("unroll") for (int mt = 0; mt < 2; ++mt) \
        _Pragma("unroll") for (int nt = 0; nt < 2; ++nt) { \
            acc[mt][nt] = __builtin_amdgcn_mfma_f32_16x16x32_bf16(a0[mt], b0[nt], acc[mt][nt], 0, 0, 0); \
            acc[mt][nt] = __builtin_amdgcn_mfma_f32_16x16x32_bf16(a0[mt], b1[nt], acc[mt][nt], 0, 0, 0); \
            acc[mt][nt] = __builtin_amdgcn_mfma_f32_16x16x32_bf16(a1[mt], b0[nt], acc[mt][nt], 0, 0, 0); \
            acc[mt][nt] = __builtin_amdgcn_mfma_f32_16x16x32_bf16(a0[mt], b2[nt], acc[mt][nt], 0, 0, 0); \
            acc[mt][nt] = __builtin_amdgcn_mfma_f32_16x16x32_bf16(a1[mt], b1[nt], acc[mt][nt], 0, 0, 0); \
            acc[mt][nt] = __builtin_amdgcn_mfma_f32_16x16x32_bf16(a2[mt], b0[nt], acc[mt][nt], 0, 0, 0); \
        } \
    }

    // epilogue: bias+relu, 3-term re-split to LDS (for next layer)
#define EPI_SPLIT3(acc, biasp, dst) \
    _Pragma("unroll") for (int mt = 0; mt < 2; ++mt) \
    _Pragma("unroll") for (int nt = 0; nt < 2; ++nt) { \
        int col = nw + nt * 16 + lrow; \
        float bv = (biasp)[col]; \
        _Pragma("unroll") for (int r = 0; r < 4; ++r) { \
            int row = mw + mt * 16 + quad * 4 + r; \
            float v = fmaxf(acc[mt][nt][r] + bv, 0.f); \
            ushort_t hh, mm, ll; split3_bf16(v, hh, mm, ll); \
            int ix = SWU(row, col); \
            (dst)[0][ix] = hh; (dst)[1][ix] = mm; (dst)[2][ix] = ll; \
        } }

    // ============ K path ============
    LOADSPLIT3(D_ + h * 64, bufA)
    __syncthreads();

    // wg for own lane, reconstructed h+m+l (repr err ~2^-27)
    float wgv;
    {
        float s = 0.f;
#pragma unroll
        for (int c8 = 0; c8 < 8; ++c8) {
            int ix = lane * 64 + ((c8 ^ (lane & 7)) << 3);
#pragma unroll
            for (int half = 0; half < 2; ++half) {
                uint2 uh = *(const uint2*)&bufA[0][ix + half * 4];
                uint2 um = *(const uint2*)&bufA[1][ix + half * 4];
                uint2 ul = *(const uint2*)&bufA[2][ix + half * 4];
                unsigned hw[4] = { uh.x & 0xffffu, uh.x >> 16, uh.y & 0xffffu, uh.y >> 16 };
                unsigned mw_[4] = { um.x & 0xffffu, um.x >> 16, um.y & 0xffffu, um.y >> 16 };
                unsigned lw[4] = { ul.x & 0xffffu, ul.x >> 16, ul.y & 0xffffu, ul.y >> 16 };
#pragma unroll
                for (int e = 0; e < 4; ++e) {
                    float kv = __uint_as_float(hw[e] << 16) + __uint_as_float(mw_[e] << 16)
                             + __uint_as_float(lw[e] << 16);
                    s += kv * wg_w[c8 * 8 + half * 4 + e];
                }
            }
        }
        s += wg_b[0];
        wgv = 1.f / (1.f + expf(-s));
    }
    float wg63 = __shfl(wgv, 63);

    {   // K L1 -> bufB (3-term split)
        f32x4 acc[2][2] = {};
        MLP_MFMA3(bufA, 2, acc)
        EPI_SPLIT3(acc, kfm_b, bufB)
    }
    __syncthreads();
    {   // K L2 -> phi_k fp32 into bufAf
        f32x4 acc[2][2] = {};
        MLP_MFMA3(bufB, 3, acc)
#pragma unroll
        for (int mt = 0; mt < 2; ++mt)
#pragma unroll
        for (int nt = 0; nt < 2; ++nt) {
            int col = nw + nt * 16 + lrow;
            float bv = kfm_b[64 + col];
#pragma unroll
            for (int r = 0; r < 4; ++r) {
                int row = mw + mt * 16 + quad * 4 + r;
                bufAf[SWF(row, col)] = fmaxf(acc[mt][nt][r] + bv, 0.f) + EPS_;
            }
        }
    }
    __syncthreads();
    // V -> bufBf (fp32, swizzled) from the preloaded registers
#pragma unroll
    for (int it = 0; it < 4; ++it) {
        int r = lr4 + it * 16;
        f32x4 t;
        t[0] = vreg[it].x; t[1] = vreg[it].y; t[2] = vreg[it].z; t[3] = vreg[it].w;
        *(f32x4*)&bufBf[SWF(r, lc4)] = t;
    }
    __syncthreads();

    // field write: write[c<64] = wg*pk*v ; write[c>=64] = wg*pk
    {
        float* frow = field + (size_t)(b * H_ + h) * 128 * F_;
        const bool last = (n0 == N_ - 64);
        for (int c = wv; c < 128; c += 4) {
            int i = lane;
            float v = (c < 64) ? wgv * bufAf[SWF(i, c)] * bufBf[SWF(i, c)]
                               : wgv * bufAf[SWF(i, c - 64)];
            if (last) {
                if (i == 62) {
                    float v2 = (c < 64) ? wg63 * bufAf[SWF(63, c)] * bufBf[SWF(63, c)]
                                        : wg63 * bufAf[SWF(63, c - 64)];
                    v += v2;
                } else if (i == 63) v = 0.f;
            }
            frow[(size_t)c * F_ + n0 + i] = v;
        }
    }
    __syncthreads();

    // ============ Q path ============
    SPLITREG3(qreg, bufA)
    __syncthreads();
    {   // Q L1 -> bufB
        f32x4 acc[2][2] = {};
        MLP_MFMA3(bufA, 0, acc)
        EPI_SPLIT3(acc, qfm_b, bufB)
    }
    __syncthreads();
    {   // Q L2 -> phi_q fp32 straight to qkvg k-columns
        f32x4 acc[2][2] = {};
        MLP_MFMA3(bufB, 1, acc)
#pragma unroll
        for (int mt = 0; mt < 2; ++mt)
#pragma unroll
        for (int nt = 0; nt < 2; ++nt) {
            int col = nw + nt * 16 + lrow;
            float bv = qfm_b[64 + col];
#pragma unroll
            for (int r = 0; r < 4; ++r) {
                int row = mw + mt * 16 + quad * 4 + r;
                qkvg[rowbase + (size_t)row * 4096 + D_ + h * 64 + col] =
                    fmaxf(acc[mt][nt][r] + bv, 0.f) + EPS_;
            }
        }
    }
#undef LOADSPLIT3
#undef SPLITREG3
#undef MLP_MFMA3
#undef EPI_SPLIT3
}

// ---------------------------------------------------------------------------
// LayerNorm of q token 0 -> q0n (B x 1024).
// ---------------------------------------------------------------------------
__global__ void kern_ln(const float* __restrict__ qkvg,
                        const float* __restrict__ ln_g,
                        const float* __restrict__ ln_b,
                        float* __restrict__ q0n) {
    const int bh = blockIdx.x, c = threadIdx.x;
    const int b = bh >> 4, h = bh & 15;
    float x = qkvg[(size_t)(b * N_) * 4096 + h * 64 + c];
    float mu = x;
    for (int m = 1; m < 64; m <<= 1) mu += __shfl_xor(mu, m);
    mu *= (1.f / 64.f);
    float dv = (x - mu) * (x - mu);
    for (int m = 1; m < 64; m <<= 1) dv += __shfl_xor(dv, m);
    float var = dv * (1.f / 64.f);
    q0n[b * 1024 + h * 64 + c] = (x - mu) * rsqrtf(var + 1e-5f) * ln_g[c] + ln_b[c];
}

// ---------------------------------------------------------------------------
// Templated table-driven radix-2 FFT helpers (used by kern_prep).
// ---------------------------------------------------------------------------
template <int NT>
__device__ __forceinline__ void fft_fwd_dif_t(float* xr, float* xi, int tid, int logn,
                                              const float2* __restrict__ twid) {
    const int nb = 1 << (logn - 1);
    for (int lh = logn - 1; lh >= 0; --lh) {
        const int hh = 1 << lh;
        const float2* tws = twid + lh * 4096;
        for (int t = tid; t < nb; t += NT) {
            int j = t & (hh - 1);
            int i1 = ((t >> lh) << (lh + 1)) | j;
            int i2 = i1 + hh;
            float2 tw = tws[t];
            float ar = xr[i1], ai = xi[i1];
            float br = xr[i2], bi = xi[i2];
            xr[i1] = ar + br; xi[i1] = ai + bi;
            float tr = ar - br, ti = ai - bi;
            xr[i2] = tr * tw.x - ti * tw.y;
            xi[i2] = tr * tw.y + ti * tw.x;
        }
        __syncthreads();
    }
}

template <int NT>
__device__ __forceinline__ void fft_inv_dit_t(float* xr, float* xi, int tid, int logn,
                                              const float2* __restrict__ twid) {
    const int nb = 1 << (logn - 1);
    for (int lh = 0; lh < logn; ++lh) {
        const int hh = 1 << lh;
        const float2* tws = twid + lh * 4096;
        for (int t = tid; t < nb; t += NT) {
            int j = t & (hh - 1);
            int i1 = ((t >> lh) << (lh + 1)) | j;
            int i2 = i1 + hh;
            float2 tw = tws[t];   // conj applied
            float br = xr[i2], bi = xi[i2];
            float tr = br * tw.x + bi * tw.y;
            float ti = bi * tw.x - br * tw.y;
            float ar = xr[i1], ai = xi[i1];
            xr[i1] = ar + tr; xi[i1] = ai + ti;
            xr[i2] = ar - tr; xi[i2] = ai - ti;
        }
        __syncthreads();
    }
}

// Padded LDS indexing for kern_prep's radix-4 helper (R2).
#define ZIDX(i) ((i) + ((i) >> 4))

// Generic radix-4 fwd stage range [SBEG, SEND) — used by kern_prep only.
template <int NT, int SBEG, int SEND>
__device__ __forceinline__ void fft4_fwd_stages(float2* z, int tid,
                                                const float2* __restrict__ tw4) {
#pragma unroll
    for (int s = SBEG; s < SEND; ++s) {
        const int q = 1024 >> (2 * s);
        const int qq = q + (q >> 4);
        const float2* tws = tw4 + s * 3072;
        for (int t = tid; t < 1024; t += NT) {
            int j = t & (q - 1);
            int base = ((t & ~(q - 1)) << 2) | j;
            int i0, i1, i2, i3;
            if (q >= 16) { i0 = ZIDX(base); i1 = i0 + qq; i2 = i1 + qq; i3 = i2 + qq; }
            else { i0 = ZIDX(base); i1 = ZIDX(base + q); i2 = ZIDX(base + 2 * q); i3 = ZIDX(base + 3 * q); }
            float2 a = z[i0], b = z[i1], c = z[i2], d = z[i3];
            float2 s0 = make_float2(a.x + c.x, a.y + c.y);
            float2 s1 = make_float2(a.x - c.x, a.y - c.y);
            float2 s2 = make_float2(b.x + d.x, b.y + d.y);
            float2 s3 = make_float2(b.x - d.x, b.y - d.y);
            float2 m1 = make_float2(s1.x + s3.y, s1.y - s3.x);
            float2 m2 = make_float2(s0.x - s2.x, s0.y - s2.y);
            float2 m3 = make_float2(s1.x - s3.y, s1.y + s3.x);
            z[i0] = make_float2(s0.x + s2.x, s0.y + s2.y);
            z[i1] = cmul(m1, tws[3 * j + 0]);
            z[i2] = cmul(m2, tws[3 * j + 1]);
            z[i3] = cmul(m3, tws[3 * j + 2]);
        }
        __syncthreads();
    }
}

// ---------------------------------------------------------------------------
// Register radix-4 butterflies for the fused conv4 (R5). Bit-exact math.
// ---------------------------------------------------------------------------
__device__ __forceinline__ void bf4_fwd(float2& e0, float2& e1, float2& e2, float2& e3,
                                        const float2* __restrict__ tws, int j) {
    float2 a = e0, b = e1, c = e2, d = e3;
    float2 s0 = make_float2(a.x + c.x, a.y + c.y);
    float2 s1 = make_float2(a.x - c.x, a.y - c.y);
    float2 s2 = make_float2(b.x + d.x, b.y + d.y);
    float2 s3 = make_float2(b.x - d.x, b.y - d.y);
    float2 m1 = make_float2(s1.x + s3.y, s1.y - s3.x);
    float2 m2 = make_float2(s0.x - s2.x, s0.y - s2.y);
    float2 m3 = make_float2(s1.x - s3.y, s1.y + s3.x);
    e0 = make_float2(s0.x + s2.x, s0.y + s2.y);
    e1 = cmul(m1, tws[3 * j + 0]);
    e2 = cmul(m2, tws[3 * j + 1]);
    e3 = cmul(m3, tws[3 * j + 2]);
}
__device__ __forceinline__ void bf4_fwd_id(float2& e0, float2& e1, float2& e2, float2& e3) {
    float2 a = e0, b = e1, c = e2, d = e3;
    float2 s0 = make_float2(a.x + c.x, a.y + c.y);
    float2 s1 = make_float2(a.x - c.x, a.y - c.y);
    float2 s2 = make_float2(b.x + d.x, b.y + d.y);
    float2 s3 = make_float2(b.x - d.x, b.y - d.y);
    e0 = make_float2(s0.x + s2.x, s0.y + s2.y);
    e1 = make_float2(s1.x + s3.y, s1.y - s3.x);
    e2 = make_float2(s0.x - s2.x, s0.y - s2.y);
    e3 = make_float2(s1.x - s3.y, s1.y + s3.x);
}
__device__ __forceinline__ void bf4_inv(float2& e0, float2& e1, float2& e2, float2& e3,
                                        const float2* __restrict__ tws, int j) {
    float2 a = e0;
    float2 b = cmulc(e1, tws[3 * j + 0]);
    float2 c = cmulc(e2, tws[3 * j + 1]);
    float2 d = cmulc(e3, tws[3 * j + 2]);
    float2 p0 = make_float2(a.x + c.x, a.y + c.y);
    float2 p1 = make_float2(a.x - c.x, a.y - c.y);
    float2 p2 = make_float2(b.x + d.x, b.y + d.y);
    float2 p3 = make_float2(b.x - d.x, b.y - d.y);
    e0 = make_float2(p0.x + p2.x, p0.y + p2.y);
    e1 = make_float2(p1.x - p3.y, p1.y + p3.x);
    e2 = make_float2(p0.x - p2.x, p0.y - p2.y);
    e3 = make_float2(p1.x + p3.y, p1.y - p3.x);
}
__device__ __forceinline__ void bf4_inv_id(float2& e0, float2& e1, float2& e2, float2& e3) {
    float2 a = e0, b = e1, c = e2, d = e3;
    float2 p0 = make_float2(a.x + c.x, a.y + c.y);
    float2 p1 = make_float2(a.x - c.x, a.y - c.y);
    float2 p2 = make_float2(b.x + d.x, b.y + d.y);
    float2 p3 = make_float2(b.x - d.x, b.y - d.y);
    e0 = make_float2(p0.x + p2.x, p0.y + p2.y);
    e1 = make_float2(p1.x - p3.y, p1.y + p3.x);
    e2 = make_float2(p0.x - p2.x, p0.y - p2.y);
    e3 = make_float2(p1.x + p3.y, p1.y - p3.x);
}

// ---------------------------------------------------------------------------
// Merged prep (1024 threads, per (b,h)): build damped-cosine kernel, fwd 8192
// FFT, apply gate in BR order, inv FFT, fold to 4096, radix-4 fwd -> GBR.
// Final radix-4 stage fused into the GBR store, 1/4096 scale folded in.
// ---------------------------------------------------------------------------
__global__ __launch_bounds__(1024) void kern_prep(const float* __restrict__ freq,
                                                  const float* __restrict__ damp,
                                                  const float* __restrict__ phase,
                                                  const float* __restrict__ ctrl,
                                                  const float2* __restrict__ twid,
                                                  const float2* __restrict__ tw4,
                                                  float* __restrict__ GBR) {
    __shared__ float sm[2 * PAD_];    // 64 KB
    float* xr = sm;
    float* xi = sm + PAD_;
    const int bh = blockIdx.x, tid = threadIdx.x;
    const int b = bh >> 4, h = bh & 15;

    // build kernel in time domain
    const float fr = freq[h], ed = expf(damp[h]), ph = phase[h];
    for (int f = tid; f < PAD_; f += 1024) {
        float v = 0.f;
        if (f < F_) {
            float t = (float)f / (float)F_;
            v = expf(-ed * t) * cosf(fr * t + ph);
        }
        xr[f] = v; xi[f] = 0.f;
    }
    __syncthreads();
    fft_fwd_dif_t<1024>(xr, xi, tid, 13, twid);   // natural -> BR spectrum

    // gate in BR order
    const float* cp = ctrl + b * (H_ * NC_) + h * NC_;
    for (int j = tid; j < PAD_; j += 1024) {
        int k = (int)(__brev((unsigned)j) >> 19);
        int kk = min(k, PAD_ - k);
        float ip = (float)kk * ((float)(NC_ - 1) / (float)(FB_ - 1));
        int il = min((int)ip, NC_ - 2);
        float iw = ip - (float)il;
        float m = 1.f + cp[il] * (1.f - iw) + cp[il + 1] * iw;
        xr[j] *= m;
        xi[j] *= m;
    }
    __syncthreads();
    fft_inv_dit_t<1024>(xr, xi, tid, 13, twid);   // BR -> natural keff (unscaled)

    // fold to 4096 real kernel, staged through registers
    float g[4];
    const float sc = 1.f / (float)PAD_;
#pragma unroll
    for (int u = 0; u < 4; ++u) {
        int j = tid + u * 1024;
        g[u] = ((j < 2048) ? xr[j] : xr[j + 4096]) * sc;
    }
    __syncthreads();
    float2* z = (float2*)sm;
#pragma unroll
    for (int u = 0; u < 4; ++u) {
        int j = tid + u * 1024;
        z[ZIDX(j)] = make_float2(g[u], 0.f);
    }
    __syncthreads();
    fft4_fwd_stages<1024, 0, 5>(z, tid, tw4);     // stages 0..4
    // fused final stage (q=1, identity twiddles) -> GBR global, scaled 1/4096
    {
        const float sc2 = 1.f / 4096.f;
        const int t = tid;   // 1024 threads, one butterfly each
        const int base = t << 2;
        float2 a = z[ZIDX(base)], bq = z[ZIDX(base + 1)];
        float2 c = z[ZIDX(base + 2)], dq = z[ZIDX(base + 3)];
        float2 s0 = make_float2(a.x + c.x, a.y + c.y);
        float2 s1 = make_float2(a.x - c.x, a.y - c.y);
        float2 s2 = make_float2(bq.x + dq.x, bq.y + dq.y);
        float2 s3 = make_float2(bq.x - dq.x, bq.y - dq.y);
        float2 o0 = make_float2(s0.x + s2.x, s0.y + s2.y);
        float2 o1 = make_float2(s1.x + s3.y, s1.y - s3.x);
        float2 o2 = make_float2(s0.x - s2.x, s0.y - s2.y);
        float2 o3 = make_float2(s1.x - s3.y, s1.y + s3.x);
        float2* Gp = (float2*)GBR + (size_t)bh * 4096 + base;
        Gp[0] = make_float2(o0.x * sc2, o0.y * sc2);
        Gp[1] = make_float2(o1.x * sc2, o1.y * sc2);
        Gp[2] = make_float2(o2.x * sc2, o2.y * sc2);
        Gp[3] = make_float2(o3.x * sc2, o3.y * sc2);
    }
}

// ---------------------------------------------------------------------------
// Main conv (R5): register-fused double stages, 5 LDS passes, 4 barriers.
// ---------------------------------------------------------------------------
#define LIDX(i) ((i) ^ (((i) >> 4) & 15))

__global__ __launch_bounds__(256) void kern_conv4(float* __restrict__ field,
                                                  const float* __restrict__ GBR,
                                                  const float2* __restrict__ tw4) {
    __shared__ float2 z[4096];
    const int tid = threadIdx.x;
    const int bh = blockIdx.x >> 6, cp = blockIdx.x & 63;
    float* rowx = field + ((size_t)bh * 128 + 2 * cp) * F_;
    float* rowy = rowx + F_;
    const float2* tws0 = tw4;
    const float2* tws1 = tw4 + 3072;
    const float2* tws2 = tw4 + 2 * 3072;
    const float2* tws3 = tw4 + 3 * 3072;
    const float2* tws4s = tw4 + 4 * 3072;

    float2 x[16];

    // ---- P1: load + fwd stages 0 (q=1024), 1 (q=256) ----
    {
        const int j16 = tid;
#pragma unroll
        for (int m = 0; m < 8; ++m)
            x[m] = make_float2(rowx[j16 + 256 * m], rowy[j16 + 256 * m]);
#pragma unroll
        for (int m = 8; m < 16; ++m) x[m] = make_float2(0.f, 0.f);
#pragma unroll
        for (int r = 0; r < 4; ++r)
            bf4_fwd(x[r], x[r + 4], x[r + 8], x[r + 12], tws0, j16 + 256 * r);
#pragma unroll
        for (int c = 0; c < 4; ++c)
            bf4_fwd(x[4 * c], x[4 * c + 1], x[4 * c + 2], x[4 * c + 3], tws1, j16);
#pragma unroll
        for (int m = 0; m < 16; ++m) z[LIDX(j16 + 256 * m)] = x[m];
    }
    __syncthreads();

    // ---- P2: fwd stages 2 (q=64), 3 (q=16) ----
    {
        const int j16 = tid & 15;
        const int pb = (tid >> 4) * 256 + j16;
#pragma unroll
        for (int m = 0; m < 16; ++m) x[m] = z[LIDX(pb + 16 * m)];
#pragma unroll
        for (int r = 0; r < 4; ++r)
            bf4_fwd(x[r], x[r + 4], x[r + 8], x[r + 12], tws2, j16 + 16 * r);
#pragma unroll
        for (int c = 0; c < 4; ++c)
            bf4_fwd(x[4 * c], x[4 * c + 1], x[4 * c + 2], x[4 * c + 3], tws3, j16);
#pragma unroll
        for (int m = 0; m < 16; ++m) z[LIDX(pb + 16 * m)] = x[m];
    }
    __syncthreads();

    // ---- P3: fwd stages 4 (q=4), 5 (q=1,id) + G + inv 5 (id), 4 ----
    {
        const int pb = tid * 16;
#pragma unroll
        for (int m = 0; m < 16; ++m) x[m] = z[LIDX(pb + m)];
#pragma unroll
        for (int r = 0; r < 4; ++r)
            bf4_fwd(x[r], x[r + 4], x[r + 8], x[r + 12], tws4s, r);
#pragma unroll
        for (int c = 0; c < 4; ++c)
            bf4_fwd_id(x[4 * c], x[4 * c + 1], x[4 * c + 2], x[4 * c + 3]);
        const float2* G = (const float2*)GBR + (size_t)bh * 4096 + pb;
#pragma unroll
        for (int m = 0; m < 16; ++m) x[m] = cmul(x[m], G[m]);
#pragma unroll
        for (int c = 0; c < 4; ++c)
            bf4_inv_id(x[4 * c], x[4 * c + 1], x[4 * c + 2], x[4 * c + 3]);
#pragma unroll
        for (int r = 0; r < 4; ++r)
            bf4_inv(x[r], x[r + 4], x[r + 8], x[r + 12], tws4s, r);
#pragma unroll
        for (int m = 0; m < 16; ++m) z[LIDX(pb + m)] = x[m];
    }
    __syncthreads();

    // ---- P4: inv stages 3 (q=16), 2 (q=64) ----
    {
        const int j16 = tid & 15;
        const int pb = (tid >> 4) * 256 + j16;
#pragma unroll
        for (int m = 0; m < 16; ++m) x[m] = z[LIDX(pb + 16 * m)];
#pragma unroll
        for (int c = 0; c < 4; ++c)
            bf4_inv(x[4 * c], x[4 * c + 1], x[4 * c + 2], x[4 * c + 3], tws3, j16);
#pragma unroll
        for (int r = 0; r < 4; ++r)
            bf4_inv(x[r], x[r + 4], x[r + 8], x[r + 12], tws2, j16 + 16 * r);
#pragma unroll
        for (int m = 0; m < 16; ++m) z[LIDX(pb + 16 * m)] = x[m];
    }
    __syncthreads();

    // ---- P5: inv stages 1 (q=256), 0 (q=1024) + store (p < 2048) ----
    {
        const int j16 = tid;
#pragma unroll
        for (int m = 0; m < 16; ++m) x[m] = z[LIDX(j16 + 256 * m)];
#pragma unroll
        for (int c = 0; c < 4; ++c)
            bf4_inv(x[4 * c], x[4 * c + 1], x[4 * c + 2], x[4 * c + 3], tws1, j16);
#pragma unroll
        for (int r = 0; r < 4; ++r)
            bf4_inv(x[r], x[r + 4], x[r + 8], x[r + 12], tws0, j16 + 256 * r);
#pragma unroll
        for (int m = 0; m < 8; ++m) {
            rowx[j16 + 256 * m] = x[m].x;
            rowy[j16 + 256 * m] = x[m].y;
        }
    }
}

// ---------------------------------------------------------------------------
// combine (LDS-staged g-plane gather from R2).
// ---------------------------------------------------------------------------
__global__ __launch_bounds__(1024) void kern_combine(float* __restrict__ qkvg,
                                                     const float* __restrict__ field,
                                                     const float* __restrict__ coupling) {
    __shared__ float cpl[16][16];
    __shared__ float sbuf[2][128][17];
    const int tid = threadIdx.x;
    if (tid < 256) cpl[tid >> 4][tid & 15] = coupling[tid];
    const int lane = tid & 63, wv = tid >> 6;
    const int n = blockIdx.x * 16 + wv;
    const int b = blockIdx.y;
    const int f0 = blockIdx.x * 16;
    const int fi = min(n, F_ - 2) - f0;   // 0..15 (last block: clamped to 14)
    const size_t row = (size_t)(b * N_ + n) * 4096;

    // loader role: c = tid>>3 (0..127), k = (tid&7)*2
    const int lc = tid >> 3, lk = (tid & 7) * 2;
    const float* fb = field + (size_t)b * 16 * 128 * F_;

    float2 rv = *(const float2*)&fb[(size_t)lc * F_ + f0 + lk];   // slice g=0
    __syncthreads();                       // cpl visible before any reads
    sbuf[0][lc][lk] = rv.x; sbuf[0][lc][lk + 1] = rv.y;

    float ynum[16], yden[16];
#pragma unroll
    for (int hh = 0; hh < 16; ++hh) { ynum[hh] = 0.f; yden[hh] = 0.f; }

    for (int g = 0; g < 16; ++g) {
        if (g < 15)
            rv = *(const float2*)&fb[((size_t)(g + 1) * 128 + lc) * F_ + f0 + lk];
        __syncthreads();                   // sbuf[g&1] writes done; prior reads of sbuf[(g+1)&1] done
        const float nv = sbuf[g & 1][lane][fi];
        const float dv = sbuf[g & 1][64 + lane][fi];
#pragma unroll
        for (int hh = 0; hh < 16; ++hh) {
            const float cg = cpl[hh][g];
            ynum[hh] += cg * nv;
            yden[hh] += cg * dv;
        }
        if (g < 15) { sbuf[(g + 1) & 1][lc][lk] = rv.x; sbuf[(g + 1) & 1][lc][lk + 1] = rv.y; }
    }

    ushort_t* rp = (ushort_t*)(qkvg + row);
#pragma unroll
    for (int hh = 0; hh < 16; ++hh) {
        float pq = qkvg[row + D_ + hh * 64 + lane];
        float gv = qkvg[row + 3 * D_ + hh * 64 + lane];
        float s = pq * yden[hh];
        for (int m = 1; m < 64; m <<= 1) s += __shfl_xor(s, m);
        float den = fabsf(s) + 1e-4f;
        float o = pq * ynum[hh] / den * (1.f / (1.f + expf(-gv)));
        ushort_t oh, ol;
        split_bf16(o, oh, ol);
        rp[hh * 64 + lane] = oh;
        rp[1024 + hh * 64 + lane] = ol;
    }
}

// ---------------------------------------------------------------------------
extern "C" void kernel_launch(void* const* d_in, const int* in_sizes, int n_in,
                              void* d_out, int out_size, void* d_ws, size_t ws_size,
                              hipStream_t stream) {
    const float* x      = (const float*)d_in[0];
    const float* w_qkvg = (const float*)d_in[1];
    const float* b_qkvg = (const float*)d_in[2];
    const float* w_out  = (const float*)d_in[3];
    const float* b_out  = (const float*)d_in[4];
    const float* qfm_w  = (const float*)d_in[5];
    const float* qfm_b  = (const float*)d_in[6];
    const float* kfm_w  = (const float*)d_in[7];
    const float* kfm_b  = (const float*)d_in[8];
    const float* wg_w   = (const float*)d_in[9];
    const float* wg_b   = (const float*)d_in[10];
    const float* ln_g   = (const float*)d_in[11];
    const float* ln_b   = (const float*)d_in[12];
    const float* sg_w1  = (const float*)d_in[13];
    const float* sg_b1  = (const float*)d_in[14];
    const float* sg_w2  = (const float*)d_in[15];
    const float* sg_b2  = (const float*)d_in[16];
    const float* wfreq  = (const float*)d_in[17];
    const float* wdamp  = (const float*)d_in[18];
    const float* wphase = (const float*)d_in[19];
    const float* coup   = (const float*)d_in[20];

    float* ws = (float*)d_ws;
    // workspace (floats):
    float*  qkvg   = ws;                 // 33,554,432
    float*  field  = ws + 33554432;      // 16,777,216
    float*  GBR    = ws + 50593792;      //    524,288
    float2* twid   = (float2*)(ws + 51118080);   // 106,496 floats (radix-2)
    float*  q0n    = ws + 51224576;      //      4,096
    float*  h1     = ws + 51228672;      //      4,096
    float*  ctrl   = ws + 51232768;      //      2,048
    ushort_t* wouth = (ushort_t*)(ws + 51234816); // 524,288 floats
    ushort_t* woutl = (ushort_t*)(ws + 51759104); // 524,288 floats
    float2* tw4    = (float2*)(ws + 52283392);    // 36,864 floats (radix-4)
    // featmap weights, 3-term bf16 split (3 x 16384 ushort = 96 KB):
    ushort_t* Wfh  = (ushort_t*)(ws + 52320256);
    ushort_t* Wfm  = Wfh + 4 * 4096;
    ushort_t* Wfl  = Wfm + 4 * 4096;
    // end: 52,344,832 floats = 209.4 MB

    // bf16 staging aliases inside `field` (consumed by gemm#1 before feat writes)
    ushort_t* xh  = (ushort_t*)(field);
    ushort_t* xl  = (ushort_t*)(field + 4194304);
    ushort_t* wqh = (ushort_t*)(field + 8388608);
    ushort_t* wql = (ushort_t*)(field + 10485760);

    // 0. twiddles + featmap weight 3-split (merged) + input splits (merged)
    kern_twid<<<(13 * 4096 + 6 * 3072 + 4 * 4096) / 256, 256, 0, stream>>>(
        twid, tw4, qfm_w, kfm_w, Wfh, Wfm, Wfl);
    kern_split3<<<(B_ * N_ * D_ + 4 * D_ * D_ + D_ * D_) / 256, 256, 0, stream>>>(
        x, xh, xl, B_ * N_ * D_,
        w_qkvg, wqh, wql, 4 * D_ * D_,
        w_out, wouth, woutl, D_ * D_);

    // 1. qkvg = x @ w_qkvg^T + b_qkvg   (split-bf16 MFMA, single launch —
    //    R3's 4-slice split ran under-occupied and cost ~100 µs)
    gemm_mfma<<<dim3(4096 / 128, 8192 / 128), 256, 0, stream>>>(
        xh, xl, D_, wqh, wql, D_, b_qkvg, qkvg, 4 * D_, D_);

    // 2. control path: LN + two M=4 GEMVs
    kern_ln<<<B_ * H_, 64, 0, stream>>>(qkvg, ln_g, ln_b, q0n);
    kern_gemv4<<<D_ / 4, 256, 0, stream>>>(q0n, sg_w1, sg_b1, h1, D_, 1);
    kern_gemv4<<<(H_ * NC_) / 4, 256, 0, stream>>>(h1, sg_w2, sg_b2, ctrl, H_ * NC_, 0);

    // 3. spectra prep (merged base FFT + gate + fold, 1024 thr)
    kern_prep<<<B_ * H_, 1024, 0, stream>>>(wfreq, wdamp, wphase, ctrl, twid, tw4, GBR);

    // 4. featmaps + wg + field build (MFMA MLPs, T14 early V/Q loads)
    kern_feat<<<dim3(N_ / 64, H_, B_), 256, 0, stream>>>(
        qkvg, Wfh, Wfm, Wfl, qfm_b, kfm_b, wg_w, wg_b, field);

    // 5. FFT convolution (register-fused radix-16 passes, 256 thr)
    kern_conv4<<<B_ * H_ * 64, 256, 0, stream>>>(field, GBR, tw4);

    // 6. combine (+fused coupling, LDS-staged) -> qkvg q-columns
    kern_combine<<<dim3(N_ / 16, B_), 1024, 0, stream>>>(qkvg, field, coup);

    // 7. out = att @ w_out^T + b_out
    gemm_mfma<<<dim3(1024 / 128, 8192 / 128), 256, 0, stream>>>(
        (ushort_t*)qkvg, (ushort_t*)qkvg + 1024, 8192,
        wouth, woutl, D_, b_out, (float*)d_out, D_, D_);
}